// Round 1
// baseline (1357.826 us; speedup 1.0000x reference)
//
#include <hip/hip_runtime.h>
#include <hip/hip_bf16.h>
#include <stdint.h>

typedef __hip_bfloat16 bf16;
using bf16x8 = __attribute__((ext_vector_type(8))) short;   // 8 bf16 (4 VGPRs)
using f32x4  = __attribute__((ext_vector_type(4))) float;   // 4 fp32

// ---------------------------------------------------------------- utilities

__device__ __forceinline__ void gload_lds16(const void* g, void* l) {
  using gchar = __attribute__((address_space(1))) char;
  using lchar = __attribute__((address_space(3))) char;
  gchar* gp = reinterpret_cast<gchar*>(reinterpret_cast<uintptr_t>(g));
  lchar* lp = reinterpret_cast<lchar*>(static_cast<uint32_t>(reinterpret_cast<uintptr_t>(l)));
  __builtin_amdgcn_global_load_lds(gp, lp, 16, 0, 0);
}

__device__ __forceinline__ unsigned short f2bf_bits(float x) {
  uint32_t u = __float_as_uint(x);
  uint32_t r = (u + 0x7fffu + ((u >> 16) & 1u)) >> 16;
  return (unsigned short)r;
}

__device__ __forceinline__ void unpack8(const int4 u, float* f) {
  uint32_t a0 = (uint32_t)u.x, a1 = (uint32_t)u.y, a2 = (uint32_t)u.z, a3 = (uint32_t)u.w;
  f[0] = __uint_as_float(a0 << 16); f[1] = __uint_as_float(a0 & 0xffff0000u);
  f[2] = __uint_as_float(a1 << 16); f[3] = __uint_as_float(a1 & 0xffff0000u);
  f[4] = __uint_as_float(a2 << 16); f[5] = __uint_as_float(a2 & 0xffff0000u);
  f[6] = __uint_as_float(a3 << 16); f[7] = __uint_as_float(a3 & 0xffff0000u);
}

// ------------------------------------------------ weight transpose fp32->bf16
// W: K x N (row major) -> Wt: N x K bf16
__global__ __launch_bounds__(256) void transpose_bf16(
    const float* __restrict__ W, bf16* __restrict__ Wt, int K, int N) {
  __shared__ float t[32][33];
  const int n0 = blockIdx.x * 32, k0 = blockIdx.y * 32;
  const int tx = threadIdx.x & 31, ty = threadIdx.x >> 5;
  #pragma unroll
  for (int i = ty; i < 32; i += 8) t[i][tx] = W[(size_t)(k0 + i) * N + n0 + tx];
  __syncthreads();
  #pragma unroll
  for (int i = ty; i < 32; i += 8)
    Wt[(size_t)(n0 + i) * K + k0 + tx] = __float2bfloat16(t[tx][i]);
}

// ------------------------------------------------ y -> bf16 (padded to 2560 rows)
__global__ __launch_bounds__(256) void conv_y(
    const float* __restrict__ y, bf16* __restrict__ yb) {
  int i = blockIdx.x * 256 + threadIdx.x;          // < 2560*1024
  float v = (i < 2464 * 1024) ? y[i] : 0.f;
  yb[i] = __float2bfloat16(v);
}

// ------------------------------------------------ ada = silu(noise) @ W_ada + b
// grid (24, 2): x = 256-col chunk, y = 16-batch half
__global__ __launch_bounds__(256) void ada_kernel(
    const float* __restrict__ noise, const float* __restrict__ W,
    const float* __restrict__ bias, float* __restrict__ ada) {
  __shared__ float s[16 * 1024];                   // 64 KB
  const int tid = threadIdx.x;
  const int b0 = blockIdx.y * 16;
  for (int i = tid; i < 16 * 1024; i += 256) {
    float v = noise[b0 * 1024 + i];
    s[i] = v / (1.f + __expf(-v));
  }
  __syncthreads();
  const int n = blockIdx.x * 256 + tid;
  float acc[16];
  #pragma unroll
  for (int i = 0; i < 16; ++i) acc[i] = 0.f;
  for (int k = 0; k < 1024; ++k) {
    float w = W[(size_t)k * 6144 + n];
    #pragma unroll
    for (int i = 0; i < 16; ++i) acc[i] += s[i * 1024 + k] * w;
  }
  float bn = bias[n];
  #pragma unroll
  for (int i = 0; i < 16; ++i) ada[(size_t)(b0 + i) * 6144 + n] = acc[i] + bn;
}

// ------------------------------------------------ LN + modulate -> bf16
__global__ __launch_bounds__(256) void ln_mod(
    const float* __restrict__ x, const float* __restrict__ ada,
    int shOff, int scOff, bf16* __restrict__ out) {
  const int row = blockIdx.x, b = row >> 8, tid = threadIdx.x;
  const float* xr = x + (size_t)row * 1024;
  float v[4], s = 0.f, ss = 0.f;
  #pragma unroll
  for (int i = 0; i < 4; ++i) {
    v[i] = xr[tid + i * 256];
    s += v[i]; ss += v[i] * v[i];
  }
  #pragma unroll
  for (int o = 32; o; o >>= 1) { s += __shfl_xor(s, o); ss += __shfl_xor(ss, o); }
  __shared__ float red[8];
  const int w = tid >> 6;
  if ((tid & 63) == 0) { red[w] = s; red[w + 4] = ss; }
  __syncthreads();
  s = red[0] + red[1] + red[2] + red[3];
  ss = red[4] + red[5] + red[6] + red[7];
  float mu = s * (1.f / 1024.f);
  float var = ss * (1.f / 1024.f) - mu * mu;
  float rstd = rsqrtf(var + 1e-6f);
  const float* adab = ada + (size_t)b * 6144;
  #pragma unroll
  for (int i = 0; i < 4; ++i) {
    int c = tid + i * 256;
    float o = (v[i] - mu) * rstd * (1.f + adab[scOff + c]) + adab[shOff + c];
    out[(size_t)row * 1024 + c] = __float2bfloat16(o);
  }
}

// ------------------------------------------------ generic bf16 MFMA GEMM
// C[M,N] = A[M,K] @ Bt[N,K]^T ; 128x128 tile, BK=64, 4 waves (64x64 each)
enum { EPI_STORE = 0, EPI_GELU = 1, EPI_PROJ = 2, EPI_OUT = 3 };

template <int EPI>
__global__ __launch_bounds__(256, 2) void gemm_bf16(
    const bf16* __restrict__ A, const bf16* __restrict__ Bt,
    int M, int N, int K,
    const float* __restrict__ bias, const float* __restrict__ ada, int adaOff,
    const float* __restrict__ resid, float* __restrict__ outF,
    bf16* __restrict__ outB) {
  (void)M;
  __shared__ bf16 As[128 * 64];
  __shared__ bf16 Bs[128 * 64];
  const int tid = threadIdx.x;
  const int w = tid >> 6, lane = tid & 63;
  const int wr = w >> 1, wc = w & 1;
  const int lr = lane >> 4, lc = lane & 15;
  const int mBase = blockIdx.y * 128, nBase = blockIdx.x * 128;

  f32x4 acc[4][4];
  #pragma unroll
  for (int mi = 0; mi < 4; ++mi)
    #pragma unroll
    for (int ni = 0; ni < 4; ++ni)
      #pragma unroll
      for (int j = 0; j < 4; ++j) acc[mi][ni][j] = 0.f;

  const int nK = K >> 6;
  for (int ks = 0; ks < nK; ++ks) {
    const int k0 = ks << 6;
    // stage A and Bt tiles: linear LDS dest, XOR-swizzled global source column
    #pragma unroll
    for (int i = 0; i < 4; ++i) {
      int t16 = w * 256 + i * 64 + lane;           // 16B chunk id 0..1023
      int row = t16 >> 3;                          // tile row 0..127
      int cL = ((t16 & 7) ^ (row & 7)) << 3;       // swizzled elem offset in row
      gload_lds16(A + (size_t)(mBase + row) * K + k0 + cL, (char*)As + t16 * 16);
      gload_lds16(Bt + (size_t)(nBase + row) * K + k0 + cL, (char*)Bs + t16 * 16);
    }
    __syncthreads();
    #pragma unroll
    for (int kk = 0; kk < 2; ++kk) {
      bf16x8 af[4], bfr[4];
      #pragma unroll
      for (int mi = 0; mi < 4; ++mi) {
        int row = wr * 64 + mi * 16 + lc;
        int byte = row * 128 + ((kk * 64 + lr * 16) ^ ((row & 7) << 4));
        af[mi] = *reinterpret_cast<const bf16x8*>((const char*)As + byte);
      }
      #pragma unroll
      for (int ni = 0; ni < 4; ++ni) {
        int row = wc * 64 + ni * 16 + lc;
        int byte = row * 128 + ((kk * 64 + lr * 16) ^ ((row & 7) << 4));
        bfr[ni] = *reinterpret_cast<const bf16x8*>((const char*)Bs + byte);
      }
      #pragma unroll
      for (int mi = 0; mi < 4; ++mi)
        #pragma unroll
        for (int ni = 0; ni < 4; ++ni)
          acc[mi][ni] = __builtin_amdgcn_mfma_f32_16x16x32_bf16(
              af[mi], bfr[ni], acc[mi][ni], 0, 0, 0);
    }
    __syncthreads();
  }

  // epilogue:  C row = (lane>>4)*4 + j, col = lane&15  (verified m89/m91 layout)
  const int rB = mBase + wr * 64, cB = nBase + wc * 64;
  #pragma unroll
  for (int mi = 0; mi < 4; ++mi) {
    #pragma unroll
    for (int ni = 0; ni < 4; ++ni) {
      #pragma unroll
      for (int j = 0; j < 4; ++j) {
        int r = rB + mi * 16 + lr * 4 + j;
        int c = cB + ni * 16 + lc;
        float v = acc[mi][ni][j];
        if (bias) v += bias[c];
        if constexpr (EPI == EPI_STORE) {
          outB[(size_t)r * N + c] = __float2bfloat16(v);
        } else if constexpr (EPI == EPI_GELU) {
          float e = __expf(1.5957691216057308f * v + 0.07135481627260086f * v * v * v);
          float t = 1.f - 2.f / (e + 1.f);         // tanh, overflow-safe
          outB[(size_t)r * N + c] = __float2bfloat16(0.5f * v * (1.f + t));
        } else if constexpr (EPI == EPI_PROJ) {
          int b = r >> 8;
          float g = ada[(size_t)b * 6144 + adaOff + c];
          float o = resid[(size_t)r * 1024 + c] + g * v;
          outF[(size_t)r * 1024 + c] = o;
          outB[(size_t)r * 1024 + c] = __float2bfloat16(o);
        } else {  // EPI_OUT
          int b = r >> 8;
          float g = ada[(size_t)b * 6144 + adaOff + c];
          outF[(size_t)r * 1024 + c] = resid[(size_t)r * 1024 + c] + g * v;
        }
      }
    }
  }
}

// ------------------------------------------------ window attention (attn1)
// one block per (b,h); thread = query row; online softmax over 16-key chunks
__global__ __launch_bounds__(256) void attn1(
    const bf16* __restrict__ qkv, const float* __restrict__ rel,
    bf16* __restrict__ o) {
  __shared__ unsigned short Ks[256 * 64];          // bf16 bits, 32 KB
  __shared__ unsigned short Vs[256 * 64];          // 32 KB
  __shared__ float bias_s[964];
  const int tid = threadIdx.x;
  const int bh = blockIdx.x, b = bh >> 4, h = bh & 15;
  const size_t base = (size_t)b * 256 * 3072;

  for (int i = tid; i < 256 * 8; i += 256) {       // 16B chunks
    int m = i >> 3, c = (i & 7) << 3;
    const int4 kd = *reinterpret_cast<const int4*>(qkv + base + (size_t)m * 3072 + 1024 + h * 64 + c);
    const int4 vd = *reinterpret_cast<const int4*>(qkv + base + (size_t)m * 3072 + 2048 + h * 64 + c);
    *reinterpret_cast<int4*>(&Ks[i * 8]) = kd;
    *reinterpret_cast<int4*>(&Vs[i * 8]) = vd;
  }
  for (int i = tid; i < 964; i += 256) bias_s[i] = rel[i * 16 + h];

  float q[64];
  {
    const bf16* qp = qkv + base + (size_t)tid * 3072 + h * 64;
    #pragma unroll
    for (int c8 = 0; c8 < 8; ++c8) {
      int4 u = *reinterpret_cast<const int4*>(qp + c8 * 8);
      float f[8]; unpack8(u, f);
      #pragma unroll
      for (int t = 0; t < 8; ++t) q[c8 * 8 + t] = f[t] * 0.125f;  // DH^-0.5
    }
  }
  __syncthreads();

  const int i1 = tid >> 4, j1 = tid & 15;
  float mmax = -3.0e38f, l = 0.f;
  float acc[64];
  #pragma unroll
  for (int d = 0; d < 64; ++d) acc[d] = 0.f;

  for (int m0 = 0; m0 < 256; m0 += 16) {
    float s[16];
    #pragma unroll
    for (int mj = 0; mj < 16; ++mj) {
      int m = m0 + mj;
      int idx = (i1 - (m >> 4) + 15) * 31 + (j1 - (m & 15) + 15);
      float sv = bias_s[idx];
      #pragma unroll
      for (int d8 = 0; d8 < 8; ++d8) {
        int4 u = *reinterpret_cast<const int4*>(&Ks[m * 64 + d8 * 8]);
        float kf[8]; unpack8(u, kf);
        #pragma unroll
        for (int t = 0; t < 8; ++t) sv += q[d8 * 8 + t] * kf[t];
      }
      s[mj] = sv;
    }
    float cmax = s[0];
    #pragma unroll
    for (int mj = 1; mj < 16; ++mj) cmax = fmaxf(cmax, s[mj]);
    float nm = fmaxf(mmax, cmax);
    float corr = __expf(mmax - nm);                // 0 on first chunk
    l *= corr;
    #pragma unroll
    for (int d = 0; d < 64; ++d) acc[d] *= corr;
    mmax = nm;
    #pragma unroll
    for (int mj = 0; mj < 16; ++mj) {
      float p = __expf(s[mj] - mmax);
      l += p;
      #pragma unroll
      for (int d8 = 0; d8 < 8; ++d8) {
        int4 u = *reinterpret_cast<const int4*>(&Vs[(m0 + mj) * 64 + d8 * 8]);
        float vf[8]; unpack8(u, vf);
        #pragma unroll
        for (int t = 0; t < 8; ++t) acc[d8 * 8 + t] += p * vf[t];
      }
    }
  }
  float inv = 1.f / l;
  bf16* op = o + ((size_t)b * 256 + tid) * 1024 + h * 64;
  #pragma unroll
  for (int d8 = 0; d8 < 8; ++d8) {
    int4 pk;
    pk.x = (int)((uint32_t)f2bf_bits(acc[d8 * 8 + 0] * inv) | ((uint32_t)f2bf_bits(acc[d8 * 8 + 1] * inv) << 16));
    pk.y = (int)((uint32_t)f2bf_bits(acc[d8 * 8 + 2] * inv) | ((uint32_t)f2bf_bits(acc[d8 * 8 + 3] * inv) << 16));
    pk.z = (int)((uint32_t)f2bf_bits(acc[d8 * 8 + 4] * inv) | ((uint32_t)f2bf_bits(acc[d8 * 8 + 5] * inv) << 16));
    pk.w = (int)((uint32_t)f2bf_bits(acc[d8 * 8 + 6] * inv) | ((uint32_t)f2bf_bits(acc[d8 * 8 + 7] * inv) << 16));
    *reinterpret_cast<int4*>(op + d8 * 8) = pk;
  }
}

// ------------------------------------------------ cross attention (attn2)
// q2 layout: col = d*16 + h ; kv: k at col d*16+h, v at 1024 + d*16+h
__global__ __launch_bounds__(256) void attn2(
    const bf16* __restrict__ q2, const bf16* __restrict__ kv,
    float* __restrict__ xcur) {
  __shared__ float Ks[77 * 64];
  __shared__ float Vs[77 * 64];
  const int bh = blockIdx.x, b = bh >> 4, h = bh & 15;
  const int tid = threadIdx.x;
  for (int i = tid; i < 77 * 64; i += 256) {
    int m = i >> 6, d = i & 63;
    size_t rowb = (size_t)(b * 77 + m) * 2048;
    Ks[i] = __bfloat162float(kv[rowb + d * 16 + h]) * 0.125f;
    Vs[i] = __bfloat162float(kv[rowb + 1024 + d * 16 + h]);
  }
  float q[64];
  {
    const bf16* qp = q2 + ((size_t)b * 256 + tid) * 1024 + h;
    #pragma unroll
    for (int d = 0; d < 64; ++d) q[d] = __bfloat162float(qp[d * 16]);
  }
  __syncthreads();

  float mmax = -3.0e38f;
  for (int m = 0; m < 77; ++m) {
    float s = 0.f;
    #pragma unroll
    for (int d4 = 0; d4 < 16; ++d4) {
      float4 kk = *reinterpret_cast<const float4*>(&Ks[m * 64 + d4 * 4]);
      s += q[d4 * 4] * kk.x + q[d4 * 4 + 1] * kk.y + q[d4 * 4 + 2] * kk.z + q[d4 * 4 + 3] * kk.w;
    }
    mmax = fmaxf(mmax, s);
  }
  float l = 0.f, acc[64];
  #pragma unroll
  for (int d = 0; d < 64; ++d) acc[d] = 0.f;
  for (int m = 0; m < 77; ++m) {
    float s = 0.f;
    #pragma unroll
    for (int d4 = 0; d4 < 16; ++d4) {
      float4 kk = *reinterpret_cast<const float4*>(&Ks[m * 64 + d4 * 4]);
      s += q[d4 * 4] * kk.x + q[d4 * 4 + 1] * kk.y + q[d4 * 4 + 2] * kk.z + q[d4 * 4 + 3] * kk.w;
    }
    float p = __expf(s - mmax);
    l += p;
    #pragma unroll
    for (int d4 = 0; d4 < 16; ++d4) {
      float4 vv = *reinterpret_cast<const float4*>(&Vs[m * 64 + d4 * 4]);
      acc[d4 * 4] += p * vv.x; acc[d4 * 4 + 1] += p * vv.y;
      acc[d4 * 4 + 2] += p * vv.z; acc[d4 * 4 + 3] += p * vv.w;
    }
  }
  float inv = 1.f / l;
  float* xp = xcur + ((size_t)b * 256 + tid) * 1024 + h;
  #pragma unroll
  for (int d = 0; d < 64; ++d) xp[d * 16] += acc[d] * inv;
}

// ---------------------------------------------------------------- launcher

extern "C" void kernel_launch(void* const* d_in, const int* in_sizes, int n_in,
                              void* d_out, int out_size, void* d_ws, size_t ws_size,
                              hipStream_t stream) {
  (void)in_sizes; (void)n_in; (void)out_size; (void)ws_size;
  const float* x      = (const float*)d_in[0];
  const float* noise  = (const float*)d_in[1];
  const float* y      = (const float*)d_in[2];
  const float* W_qkv  = (const float*)d_in[3];
  const float* b_qkv  = (const float*)d_in[4];
  const float* W_proj = (const float*)d_in[5];
  const float* b_proj = (const float*)d_in[6];
  const float* rel    = (const float*)d_in[7];
  const float* W_ada  = (const float*)d_in[8];
  const float* b_ada  = (const float*)d_in[9];
  const float* W_fc1  = (const float*)d_in[10];
  const float* b_fc1  = (const float*)d_in[11];
  const float* W_fc2  = (const float*)d_in[12];
  const float* b_fc2  = (const float*)d_in[13];
  const float* W_q    = (const float*)d_in[14];
  const float* W_kv   = (const float*)d_in[15];

  char* ws = (char*)d_ws;
  size_t off = 0;
  auto alloc = [&](size_t bytes) {
    char* p = ws + off;
    off = (off + bytes + 255) & ~(size_t)255;
    return p;
  };
  float* ada   = (float*)alloc(32u * 6144 * 4);        //  0.79 MB
  float* xcur  = (float*)alloc(8192u * 1024 * 4);      // 33.6 MB (x1 then x2)
  bf16* WqkvT  = (bf16*)alloc(3072u * 1024 * 2);
  bf16* WprojT = (bf16*)alloc(1024u * 1024 * 2);
  bf16* WqT    = (bf16*)alloc(1024u * 1024 * 2);
  bf16* WkvT   = (bf16*)alloc(2048u * 1024 * 2);
  bf16* Wfc1T  = (bf16*)alloc(4096u * 1024 * 2);
  bf16* Wfc2T  = (bf16*)alloc(1024u * 4096 * 2);
  bf16* hbuf   = (bf16*)alloc(8192u * 1024 * 2);       // ln1 out / x1 bf16 / ln2 out
  bf16* big    = (bf16*)alloc(8192u * 4096 * 2);       // qkv (50MB) then mlp-h (67MB)
  bf16* obuf   = (bf16*)alloc(8192u * 1024 * 2);       // attn1 o, then q2
  bf16* kvbuf  = (bf16*)alloc(2560u * 2048 * 2);
  bf16* ybuf   = (bf16*)alloc(2560u * 1024 * 2);       // total ~182 MB
  float* outF  = (float*)d_out;

  // weight prep
  transpose_bf16<<<dim3(96, 32), 256, 0, stream>>>(W_qkv, WqkvT, 1024, 3072);
  transpose_bf16<<<dim3(32, 32), 256, 0, stream>>>(W_proj, WprojT, 1024, 1024);
  transpose_bf16<<<dim3(32, 32), 256, 0, stream>>>(W_q, WqT, 1024, 1024);
  transpose_bf16<<<dim3(64, 32), 256, 0, stream>>>(W_kv, WkvT, 1024, 2048);
  transpose_bf16<<<dim3(128, 32), 256, 0, stream>>>(W_fc1, Wfc1T, 1024, 4096);
  transpose_bf16<<<dim3(32, 128), 256, 0, stream>>>(W_fc2, Wfc2T, 4096, 1024);
  conv_y<<<2560 * 1024 / 256, 256, 0, stream>>>(y, ybuf);
  ada_kernel<<<dim3(24, 2), 256, 0, stream>>>(noise, W_ada, b_ada, ada);

  // MSA branch
  ln_mod<<<8192, 256, 0, stream>>>(x, ada, 0, 1024, hbuf);
  gemm_bf16<EPI_STORE><<<dim3(24, 64), 256, 0, stream>>>(
      hbuf, WqkvT, 8192, 3072, 1024, b_qkv, nullptr, 0, nullptr, nullptr, big);
  attn1<<<512, 256, 0, stream>>>(big, rel, obuf);
  gemm_bf16<EPI_PROJ><<<dim3(8, 64), 256, 0, stream>>>(
      obuf, WprojT, 8192, 1024, 1024, b_proj, ada, 2048, x, xcur, hbuf);

  // cross-attention branch
  gemm_bf16<EPI_STORE><<<dim3(8, 64), 256, 0, stream>>>(
      hbuf, WqT, 8192, 1024, 1024, nullptr, nullptr, 0, nullptr, nullptr, obuf);
  gemm_bf16<EPI_STORE><<<dim3(16, 20), 256, 0, stream>>>(
      ybuf, WkvT, 2560, 2048, 1024, nullptr, nullptr, 0, nullptr, nullptr, kvbuf);
  attn2<<<512, 256, 0, stream>>>(obuf, kvbuf, xcur);

  // MLP branch
  ln_mod<<<8192, 256, 0, stream>>>(xcur, ada, 3072, 4096, hbuf);
  gemm_bf16<EPI_GELU><<<dim3(32, 64), 256, 0, stream>>>(
      hbuf, Wfc1T, 8192, 4096, 1024, b_fc1, nullptr, 0, nullptr, nullptr, big);
  gemm_bf16<EPI_OUT><<<dim3(8, 64), 256, 0, stream>>>(
      big, Wfc2T, 8192, 1024, 4096, b_fc2, ada, 5120, xcur, outF, nullptr);
}

// Round 2
// 950.019 us; speedup vs baseline: 1.4293x; 1.4293x over previous
//
#include <hip/hip_runtime.h>
#include <hip/hip_bf16.h>
#include <stdint.h>

typedef __hip_bfloat16 bf16;
using bf16x8 = __attribute__((ext_vector_type(8))) short;   // 8 bf16 (4 VGPRs)
using f32x4  = __attribute__((ext_vector_type(4))) float;   // 4 fp32

// ---------------------------------------------------------------- utilities

__device__ __forceinline__ void gload_lds16(const void* g, void* l) {
  using gchar = __attribute__((address_space(1))) char;
  using lchar = __attribute__((address_space(3))) char;
  gchar* gp = reinterpret_cast<gchar*>(reinterpret_cast<uintptr_t>(g));
  lchar* lp = reinterpret_cast<lchar*>(static_cast<uint32_t>(reinterpret_cast<uintptr_t>(l)));
  __builtin_amdgcn_global_load_lds(gp, lp, 16, 0, 0);
}

__device__ __forceinline__ unsigned short f2bf_bits(float x) {
  uint32_t u = __float_as_uint(x);
  uint32_t r = (u + 0x7fffu + ((u >> 16) & 1u)) >> 16;
  return (unsigned short)r;
}

// ------------------------------------------------ weight transpose fp32->bf16
// W: K x N (row major) -> Wt: N x K bf16
__global__ __launch_bounds__(256) void transpose_bf16(
    const float* __restrict__ W, bf16* __restrict__ Wt, int K, int N) {
  __shared__ float t[32][33];
  const int n0 = blockIdx.x * 32, k0 = blockIdx.y * 32;
  const int tx = threadIdx.x & 31, ty = threadIdx.x >> 5;
  #pragma unroll
  for (int i = ty; i < 32; i += 8) t[i][tx] = W[(size_t)(k0 + i) * N + n0 + tx];
  __syncthreads();
  #pragma unroll
  for (int i = ty; i < 32; i += 8)
    Wt[(size_t)(n0 + i) * K + k0 + tx] = __float2bfloat16(t[tx][i]);
}

// ------------------------------------------------ y -> bf16 (padded to 2560 rows)
__global__ __launch_bounds__(256) void conv_y(
    const float* __restrict__ y, bf16* __restrict__ yb) {
  int i = blockIdx.x * 256 + threadIdx.x;          // < 2560*1024
  float v = (i < 2464 * 1024) ? y[i] : 0.f;
  yb[i] = __float2bfloat16(v);
}

// ------------------------------------------------ ada = silu(noise) @ W_ada + b
__global__ __launch_bounds__(256) void ada_kernel(
    const float* __restrict__ noise, const float* __restrict__ W,
    const float* __restrict__ bias, float* __restrict__ ada) {
  __shared__ float s[16 * 1024];                   // 64 KB
  const int tid = threadIdx.x;
  const int b0 = blockIdx.y * 16;
  for (int i = tid; i < 16 * 1024; i += 256) {
    float v = noise[b0 * 1024 + i];
    s[i] = v / (1.f + __expf(-v));
  }
  __syncthreads();
  const int n = blockIdx.x * 256 + tid;
  float acc[16];
  #pragma unroll
  for (int i = 0; i < 16; ++i) acc[i] = 0.f;
  for (int k = 0; k < 1024; ++k) {
    float w = W[(size_t)k * 6144 + n];
    #pragma unroll
    for (int i = 0; i < 16; ++i) acc[i] += s[i * 1024 + k] * w;
  }
  float bn = bias[n];
  #pragma unroll
  for (int i = 0; i < 16; ++i) ada[(size_t)(b0 + i) * 6144 + n] = acc[i] + bn;
}

// ------------------------------------------------ LN + modulate -> bf16
__global__ __launch_bounds__(256) void ln_mod(
    const float* __restrict__ x, const float* __restrict__ ada,
    int shOff, int scOff, bf16* __restrict__ out) {
  const int row = blockIdx.x, b = row >> 8, tid = threadIdx.x;
  const float* xr = x + (size_t)row * 1024;
  float v[4], s = 0.f, ss = 0.f;
  #pragma unroll
  for (int i = 0; i < 4; ++i) {
    v[i] = xr[tid + i * 256];
    s += v[i]; ss += v[i] * v[i];
  }
  #pragma unroll
  for (int o = 32; o; o >>= 1) { s += __shfl_xor(s, o); ss += __shfl_xor(ss, o); }
  __shared__ float red[8];
  const int w = tid >> 6;
  if ((tid & 63) == 0) { red[w] = s; red[w + 4] = ss; }
  __syncthreads();
  s = red[0] + red[1] + red[2] + red[3];
  ss = red[4] + red[5] + red[6] + red[7];
  float mu = s * (1.f / 1024.f);
  float var = ss * (1.f / 1024.f) - mu * mu;
  float rstd = rsqrtf(var + 1e-6f);
  const float* adab = ada + (size_t)b * 6144;
  #pragma unroll
  for (int i = 0; i < 4; ++i) {
    int c = tid + i * 256;
    float o = (v[i] - mu) * rstd * (1.f + adab[scOff + c]) + adab[shOff + c];
    out[(size_t)row * 1024 + c] = __float2bfloat16(o);
  }
}

// ------------------------------------------------ generic bf16 MFMA GEMM
// C[M,N] = A[M,K] @ Bt[N,K]^T ; 128x128 tile, BK=64, 4 waves (64x64 each)
enum { EPI_STORE = 0, EPI_GELU = 1, EPI_PROJ = 2, EPI_OUT = 3 };

template <int EPI>
__global__ __launch_bounds__(256, 2) void gemm_bf16(
    const bf16* __restrict__ A, const bf16* __restrict__ Bt,
    int M, int N, int K,
    const float* __restrict__ bias, const float* __restrict__ ada, int adaOff,
    const float* __restrict__ resid, float* __restrict__ outF,
    bf16* __restrict__ outB) {
  (void)M;
  __shared__ bf16 As[128 * 64];
  __shared__ bf16 Bs[128 * 64];
  const int tid = threadIdx.x;
  const int w = tid >> 6, lane = tid & 63;
  const int wr = w >> 1, wc = w & 1;
  const int lr = lane >> 4, lc = lane & 15;
  const int mBase = blockIdx.y * 128, nBase = blockIdx.x * 128;

  f32x4 acc[4][4];
  #pragma unroll
  for (int mi = 0; mi < 4; ++mi)
    #pragma unroll
    for (int ni = 0; ni < 4; ++ni)
      #pragma unroll
      for (int j = 0; j < 4; ++j) acc[mi][ni][j] = 0.f;

  const int nK = K >> 6;
  for (int ks = 0; ks < nK; ++ks) {
    const int k0 = ks << 6;
    #pragma unroll
    for (int i = 0; i < 4; ++i) {
      int t16 = w * 256 + i * 64 + lane;           // 16B chunk id 0..1023
      int row = t16 >> 3;                          // tile row 0..127
      int cL = ((t16 & 7) ^ (row & 7)) << 3;       // swizzled elem offset in row
      gload_lds16(A + (size_t)(mBase + row) * K + k0 + cL, (char*)As + t16 * 16);
      gload_lds16(Bt + (size_t)(nBase + row) * K + k0 + cL, (char*)Bs + t16 * 16);
    }
    __syncthreads();
    #pragma unroll
    for (int kk = 0; kk < 2; ++kk) {
      bf16x8 af[4], bfr[4];
      #pragma unroll
      for (int mi = 0; mi < 4; ++mi) {
        int row = wr * 64 + mi * 16 + lc;
        int byte = row * 128 + ((kk * 64 + lr * 16) ^ ((row & 7) << 4));
        af[mi] = *reinterpret_cast<const bf16x8*>((const char*)As + byte);
      }
      #pragma unroll
      for (int ni = 0; ni < 4; ++ni) {
        int row = wc * 64 + ni * 16 + lc;
        int byte = row * 128 + ((kk * 64 + lr * 16) ^ ((row & 7) << 4));
        bfr[ni] = *reinterpret_cast<const bf16x8*>((const char*)Bs + byte);
      }
      #pragma unroll
      for (int mi = 0; mi < 4; ++mi)
        #pragma unroll
        for (int ni = 0; ni < 4; ++ni)
          acc[mi][ni] = __builtin_amdgcn_mfma_f32_16x16x32_bf16(
              af[mi], bfr[ni], acc[mi][ni], 0, 0, 0);
    }
    __syncthreads();
  }

  const int rB = mBase + wr * 64, cB = nBase + wc * 64;
  #pragma unroll
  for (int mi = 0; mi < 4; ++mi) {
    #pragma unroll
    for (int ni = 0; ni < 4; ++ni) {
      #pragma unroll
      for (int j = 0; j < 4; ++j) {
        int r = rB + mi * 16 + lr * 4 + j;
        int c = cB + ni * 16 + lc;
        float v = acc[mi][ni][j];
        if (bias) v += bias[c];
        if constexpr (EPI == EPI_STORE) {
          outB[(size_t)r * N + c] = __float2bfloat16(v);
        } else if constexpr (EPI == EPI_GELU) {
          float e = __expf(1.5957691216057308f * v + 0.07135481627260086f * v * v * v);
          float t = 1.f - 2.f / (e + 1.f);         // tanh, overflow-safe
          outB[(size_t)r * N + c] = __float2bfloat16(0.5f * v * (1.f + t));
        } else if constexpr (EPI == EPI_PROJ) {
          int b = r >> 8;
          float g = ada[(size_t)b * 6144 + adaOff + c];
          float o = resid[(size_t)r * 1024 + c] + g * v;
          outF[(size_t)r * 1024 + c] = o;
          outB[(size_t)r * 1024 + c] = __float2bfloat16(o);
        } else {  // EPI_OUT
          int b = r >> 8;
          float g = ada[(size_t)b * 6144 + adaOff + c];
          outF[(size_t)r * 1024 + c] = resid[(size_t)r * 1024 + c] + g * v;
        }
      }
    }
  }
}

// ------------------------------------------------ window attention (attn1, MFMA)
// block = (b,h), 8 waves x 32 q-rows; flash over 8 key-tiles of 32.
// qkv layout: [b][n][3][h][dh], row stride 3072.
__global__ __launch_bounds__(512, 1) void attn1_mfma(
    const bf16* __restrict__ qkv, const float* __restrict__ rel,
    bf16* __restrict__ o) {
  __shared__ bf16 Ks[256 * 64];          // rows XOR-swizzled in 16B chunks
  __shared__ bf16 Vt[64 * 256];          // V transposed [dh][key], XOR-swizzled
  __shared__ ushort Pl[8][32 * 40];      // per-wave P (bf16 bits), stride 40
  __shared__ float bias_s[964];

  const int tid = threadIdx.x;
  const int w = tid >> 6, lane = tid & 63;
  const int p4 = lane >> 4, c = lane & 15;
  const int bh = blockIdx.x, b = bh >> 4, h = bh & 15;
  const bf16* basep = qkv + (size_t)b * 256 * 3072 + h * 64;

  // --- stage K via global_load_lds, pre-swizzled source column (rule #21)
  #pragma unroll
  for (int it = 0; it < 4; ++it) {
    int t16 = it * 512 + tid;                       // 0..2047
    int row = t16 >> 3;
    int sc = ((t16 & 7) ^ (row & 7)) << 3;
    gload_lds16(basep + (size_t)row * 3072 + 1024 + sc, (char*)Ks + t16 * 16);
  }
  // --- stage V transposed with XOR swizzle on key-chunk bits
  #pragma unroll
  for (int it = 0; it < 4; ++it) {
    int i = it * 512 + tid;                         // chunk id 0..2047
    int key = i >> 3, d0 = (i & 7) * 8;
    int4 u = *reinterpret_cast<const int4*>(basep + (size_t)key * 3072 + 2048 + d0);
    const ushort* us = reinterpret_cast<const ushort*>(&u);
    #pragma unroll
    for (int j = 0; j < 8; ++j) {
      int dh = d0 + j;
      int byte = dh * 512 + ((key * 2) ^ ((dh & 7) << 4));
      *reinterpret_cast<ushort*>((char*)Vt + byte) = us[j];
    }
  }
  for (int i = tid; i < 964; i += 512) bias_s[i] = rel[i * 16 + h];

  // --- Q fragments, pre-scaled by DH^-0.5 = 0.125 (exact exp shift)
  bf16x8 qf[2][2];
  #pragma unroll
  for (int mi = 0; mi < 2; ++mi)
    #pragma unroll
    for (int s = 0; s < 2; ++s) {
      int q = w * 32 + mi * 16 + c;
      int dh = s * 32 + p4 * 8;
      int4 u = *reinterpret_cast<const int4*>(basep + (size_t)q * 3072 + dh);
      uint32_t a[4] = {(uint32_t)u.x, (uint32_t)u.y, (uint32_t)u.z, (uint32_t)u.w};
      bf16x8 r;
      #pragma unroll
      for (int t = 0; t < 4; ++t) {
        float lo = __uint_as_float(a[t] << 16) * 0.125f;
        float hi = __uint_as_float(a[t] & 0xffff0000u) * 0.125f;
        r[2 * t]     = (short)(__float_as_uint(lo) >> 16);   // exact
        r[2 * t + 1] = (short)(__float_as_uint(hi) >> 16);
      }
      qf[mi][s] = r;
    }
  __syncthreads();

  float m_run[2][4], l_run[2][4];
  f32x4 oacc[2][4];
  #pragma unroll
  for (int mi = 0; mi < 2; ++mi)
    #pragma unroll
    for (int j = 0; j < 4; ++j) {
      m_run[mi][j] = -1e30f; l_run[mi][j] = 0.f;
      oacc[mi][j] = f32x4{0.f, 0.f, 0.f, 0.f};
    }

  ushort* Pw = &Pl[w][0];
  const int colterm = p4 * 4 - c + 15;

  for (int kt = 0; kt < 8; ++kt) {
    // S init = rel bias (scores = qk*scale + bias; Q pre-scaled)
    f32x4 sacc[2][2];
    #pragma unroll
    for (int mi = 0; mi < 2; ++mi)
      #pragma unroll
      for (int nf = 0; nf < 2; ++nf) {
        int bi = ((w * 2 + mi) - (kt * 2 + nf) + 15) * 31 + colterm;
        #pragma unroll
        for (int j = 0; j < 4; ++j) sacc[mi][nf][j] = bias_s[bi + j];
      }
    // QK^T
    #pragma unroll
    for (int nf = 0; nf < 2; ++nf) {
      int key = kt * 32 + nf * 16 + c;
      #pragma unroll
      for (int s = 0; s < 2; ++s) {
        int byte = key * 128 + (((s * 4 + p4) ^ (key & 7)) << 4);
        bf16x8 kb = *reinterpret_cast<const bf16x8*>((const char*)Ks + byte);
        #pragma unroll
        for (int mi = 0; mi < 2; ++mi)
          sacc[mi][nf] = __builtin_amdgcn_mfma_f32_16x16x32_bf16(
              qf[mi][s], kb, sacc[mi][nf], 0, 0, 0);
      }
    }
    // row stats + rescale
    float sf[2][4];
    #pragma unroll
    for (int mi = 0; mi < 2; ++mi)
      #pragma unroll
      for (int j = 0; j < 4; ++j) {
        float cm = fmaxf(sacc[mi][0][j], sacc[mi][1][j]);
        cm = fmaxf(cm, __shfl_xor(cm, 1));
        cm = fmaxf(cm, __shfl_xor(cm, 2));
        cm = fmaxf(cm, __shfl_xor(cm, 4));
        cm = fmaxf(cm, __shfl_xor(cm, 8));
        float nm = fmaxf(m_run[mi][j], cm);
        sf[mi][j] = __expf(m_run[mi][j] - nm);
        m_run[mi][j] = nm;
        l_run[mi][j] *= sf[mi][j];
      }
    #pragma unroll
    for (int mi = 0; mi < 2; ++mi)
      #pragma unroll
      for (int nf = 0; nf < 4; ++nf)
        #pragma unroll
        for (int j = 0; j < 4; ++j) oacc[mi][nf][j] *= sf[mi][j];
    // P = exp(S - m), l accumulation, pack to LDS
    #pragma unroll
    for (int mi = 0; mi < 2; ++mi) {
      #pragma unroll
      for (int nf = 0; nf < 2; ++nf)
        #pragma unroll
        for (int j = 0; j < 4; ++j)
          sacc[mi][nf][j] = __expf(sacc[mi][nf][j] - m_run[mi][j]);
      #pragma unroll
      for (int j = 0; j < 4; ++j) {
        float lp = sacc[mi][0][j] + sacc[mi][1][j];
        lp += __shfl_xor(lp, 1);
        lp += __shfl_xor(lp, 2);
        lp += __shfl_xor(lp, 4);
        lp += __shfl_xor(lp, 8);
        l_run[mi][j] += lp;
      }
      #pragma unroll
      for (int nf = 0; nf < 2; ++nf)
        #pragma unroll
        for (int j = 0; j < 4; ++j)
          Pw[(mi * 16 + p4 * 4 + j) * 40 + nf * 16 + c] =
              f2bf_bits(sacc[mi][nf][j]);
    }
    // PV: A = P (per-wave LDS), B = Vt (swizzled)
    bf16x8 pa[2], vb[4];
    #pragma unroll
    for (int mi = 0; mi < 2; ++mi)
      pa[mi] = *reinterpret_cast<const bf16x8*>(
          (const char*)Pw + (mi * 16 + c) * 80 + p4 * 16);
    #pragma unroll
    for (int nf = 0; nf < 4; ++nf) {
      int dh = nf * 16 + c;
      int byte = dh * 512 + (((kt * 4 + p4) ^ (dh & 7)) << 4);
      vb[nf] = *reinterpret_cast<const bf16x8*>((const char*)Vt + byte);
    }
    #pragma unroll
    for (int mi = 0; mi < 2; ++mi)
      #pragma unroll
      for (int nf = 0; nf < 4; ++nf)
        oacc[mi][nf] = __builtin_amdgcn_mfma_f32_16x16x32_bf16(
            pa[mi], vb[nf], oacc[mi][nf], 0, 0, 0);
  }

  // output: o[b][q][h*64+dh], row = p4*4+j, col = c
  #pragma unroll
  for (int mi = 0; mi < 2; ++mi) {
    float inv[4];
    #pragma unroll
    for (int j = 0; j < 4; ++j) inv[j] = 1.f / l_run[mi][j];
    #pragma unroll
    for (int nf = 0; nf < 4; ++nf)
      #pragma unroll
      for (int j = 0; j < 4; ++j) {
        int q = w * 32 + mi * 16 + p4 * 4 + j;
        int dh = nf * 16 + c;
        o[((size_t)b * 256 + q) * 1024 + h * 64 + dh] =
            __float2bfloat16(oacc[mi][nf][j] * inv[j]);
      }
  }
}

// ------------------------------------------------ cross attention (attn2)
// q2 layout: col = d*16 + h ; kv: k at col d*16+h, v at 1024 + d*16+h
__global__ __launch_bounds__(256) void attn2(
    const bf16* __restrict__ q2, const bf16* __restrict__ kv,
    float* __restrict__ xcur) {
  __shared__ float Ks[77 * 64];
  __shared__ float Vs[77 * 64];
  const int bh = blockIdx.x, b = bh >> 4, h = bh & 15;
  const int tid = threadIdx.x;
  for (int i = tid; i < 77 * 64; i += 256) {
    int m = i >> 6, d = i & 63;
    size_t rowb = (size_t)(b * 77 + m) * 2048;
    Ks[i] = __bfloat162float(kv[rowb + d * 16 + h]) * 0.125f;
    Vs[i] = __bfloat162float(kv[rowb + 1024 + d * 16 + h]);
  }
  float q[64];
  {
    const bf16* qp = q2 + ((size_t)b * 256 + tid) * 1024 + h;
    #pragma unroll
    for (int d = 0; d < 64; ++d) q[d] = __bfloat162float(qp[d * 16]);
  }
  __syncthreads();

  float mmax = -3.0e38f;
  for (int m = 0; m < 77; ++m) {
    float s = 0.f;
    #pragma unroll
    for (int d4 = 0; d4 < 16; ++d4) {
      float4 kk = *reinterpret_cast<const float4*>(&Ks[m * 64 + d4 * 4]);
      s += q[d4 * 4] * kk.x + q[d4 * 4 + 1] * kk.y + q[d4 * 4 + 2] * kk.z + q[d4 * 4 + 3] * kk.w;
    }
    mmax = fmaxf(mmax, s);
  }
  float l = 0.f, acc[64];
  #pragma unroll
  for (int d = 0; d < 64; ++d) acc[d] = 0.f;
  for (int m = 0; m < 77; ++m) {
    float s = 0.f;
    #pragma unroll
    for (int d4 = 0; d4 < 16; ++d4) {
      float4 kk = *reinterpret_cast<const float4*>(&Ks[m * 64 + d4 * 4]);
      s += q[d4 * 4] * kk.x + q[d4 * 4 + 1] * kk.y + q[d4 * 4 + 2] * kk.z + q[d4 * 4 + 3] * kk.w;
    }
    float p = __expf(s - mmax);
    l += p;
    #pragma unroll
    for (int d4 = 0; d4 < 16; ++d4) {
      float4 vv = *reinterpret_cast<const float4*>(&Vs[m * 64 + d4 * 4]);
      acc[d4 * 4] += p * vv.x; acc[d4 * 4 + 1] += p * vv.y;
      acc[d4 * 4 + 2] += p * vv.z; acc[d4 * 4 + 3] += p * vv.w;
    }
  }
  float inv = 1.f / l;
  float* xp = xcur + ((size_t)b * 256 + tid) * 1024 + h;
  #pragma unroll
  for (int d = 0; d < 64; ++d) xp[d * 16] += acc[d] * inv;
}

// ---------------------------------------------------------------- launcher

extern "C" void kernel_launch(void* const* d_in, const int* in_sizes, int n_in,
                              void* d_out, int out_size, void* d_ws, size_t ws_size,
                              hipStream_t stream) {
  (void)in_sizes; (void)n_in; (void)out_size; (void)ws_size;
  const float* x      = (const float*)d_in[0];
  const float* noise  = (const float*)d_in[1];
  const float* y      = (const float*)d_in[2];
  const float* W_qkv  = (const float*)d_in[3];
  const float* b_qkv  = (const float*)d_in[4];
  const float* W_proj = (const float*)d_in[5];
  const float* b_proj = (const float*)d_in[6];
  const float* rel    = (const float*)d_in[7];
  const float* W_ada  = (const float*)d_in[8];
  const float* b_ada  = (const float*)d_in[9];
  const float* W_fc1  = (const float*)d_in[10];
  const float* b_fc1  = (const float*)d_in[11];
  const float* W_fc2  = (const float*)d_in[12];
  const float* b_fc2  = (const float*)d_in[13];
  const float* W_q    = (const float*)d_in[14];
  const float* W_kv   = (const float*)d_in[15];

  char* ws = (char*)d_ws;
  size_t off = 0;
  auto alloc = [&](size_t bytes) {
    char* p = ws + off;
    off = (off + bytes + 255) & ~(size_t)255;
    return p;
  };
  float* ada   = (float*)alloc(32u * 6144 * 4);
  float* xcur  = (float*)alloc(8192u * 1024 * 4);
  bf16* WqkvT  = (bf16*)alloc(3072u * 1024 * 2);
  bf16* WprojT = (bf16*)alloc(1024u * 1024 * 2);
  bf16* WqT    = (bf16*)alloc(1024u * 1024 * 2);
  bf16* WkvT   = (bf16*)alloc(2048u * 1024 * 2);
  bf16* Wfc1T  = (bf16*)alloc(4096u * 1024 * 2);
  bf16* Wfc2T  = (bf16*)alloc(1024u * 4096 * 2);
  bf16* hbuf   = (bf16*)alloc(8192u * 1024 * 2);
  bf16* big    = (bf16*)alloc(8192u * 4096 * 2);
  bf16* obuf   = (bf16*)alloc(8192u * 1024 * 2);
  bf16* kvbuf  = (bf16*)alloc(2560u * 2048 * 2);
  bf16* ybuf   = (bf16*)alloc(2560u * 1024 * 2);
  float* outF  = (float*)d_out;

  // weight prep
  transpose_bf16<<<dim3(96, 32), 256, 0, stream>>>(W_qkv, WqkvT, 1024, 3072);
  transpose_bf16<<<dim3(32, 32), 256, 0, stream>>>(W_proj, WprojT, 1024, 1024);
  transpose_bf16<<<dim3(32, 32), 256, 0, stream>>>(W_q, WqT, 1024, 1024);
  transpose_bf16<<<dim3(64, 32), 256, 0, stream>>>(W_kv, WkvT, 1024, 2048);
  transpose_bf16<<<dim3(128, 32), 256, 0, stream>>>(W_fc1, Wfc1T, 1024, 4096);
  transpose_bf16<<<dim3(32, 128), 256, 0, stream>>>(W_fc2, Wfc2T, 4096, 1024);
  conv_y<<<2560 * 1024 / 256, 256, 0, stream>>>(y, ybuf);
  ada_kernel<<<dim3(24, 2), 256, 0, stream>>>(noise, W_ada, b_ada, ada);

  // MSA branch
  ln_mod<<<8192, 256, 0, stream>>>(x, ada, 0, 1024, hbuf);
  gemm_bf16<EPI_STORE><<<dim3(24, 64), 256, 0, stream>>>(
      hbuf, WqkvT, 8192, 3072, 1024, b_qkv, nullptr, 0, nullptr, nullptr, big);
  attn1_mfma<<<512, 512, 0, stream>>>(big, rel, obuf);
  gemm_bf16<EPI_PROJ><<<dim3(8, 64), 256, 0, stream>>>(
      obuf, WprojT, 8192, 1024, 1024, b_proj, ada, 2048, x, xcur, hbuf);

  // cross-attention branch
  gemm_bf16<EPI_STORE><<<dim3(8, 64), 256, 0, stream>>>(
      hbuf, WqT, 8192, 1024, 1024, nullptr, nullptr, 0, nullptr, nullptr, obuf);
  gemm_bf16<EPI_STORE><<<dim3(16, 20), 256, 0, stream>>>(
      ybuf, WkvT, 2560, 2048, 1024, nullptr, nullptr, 0, nullptr, nullptr, kvbuf);
  attn2<<<512, 256, 0, stream>>>(obuf, kvbuf, xcur);

  // MLP branch
  ln_mod<<<8192, 256, 0, stream>>>(xcur, ada, 3072, 4096, hbuf);
  gemm_bf16<EPI_GELU><<<dim3(32, 64), 256, 0, stream>>>(
      hbuf, Wfc1T, 8192, 4096, 1024, b_fc1, nullptr, 0, nullptr, nullptr, big);
  gemm_bf16<EPI_OUT><<<dim3(8, 64), 256, 0, stream>>>(
      big, Wfc2T, 8192, 1024, 4096, b_fc2, ada, 5120, xcur, outF, nullptr);
}

// Round 3
// 679.711 us; speedup vs baseline: 1.9977x; 1.3977x over previous
//
#include <hip/hip_runtime.h>
#include <hip/hip_bf16.h>
#include <stdint.h>

typedef __hip_bfloat16 bf16;
using bf16x8 = __attribute__((ext_vector_type(8))) short;   // 8 bf16 (4 VGPRs)
using f32x4  = __attribute__((ext_vector_type(4))) float;   // 4 fp32

// ---------------------------------------------------------------- utilities

__device__ __forceinline__ void gload_lds16(const void* g, void* l) {
  using gchar = __attribute__((address_space(1))) char;
  using lchar = __attribute__((address_space(3))) char;
  gchar* gp = reinterpret_cast<gchar*>(reinterpret_cast<uintptr_t>(g));
  lchar* lp = reinterpret_cast<lchar*>(static_cast<uint32_t>(reinterpret_cast<uintptr_t>(l)));
  __builtin_amdgcn_global_load_lds(gp, lp, 16, 0, 0);
}

__device__ __forceinline__ unsigned short f2bf_bits(float x) {
  uint32_t u = __float_as_uint(x);
  uint32_t r = (u + 0x7fffu + ((u >> 16) & 1u)) >> 16;
  return (unsigned short)r;
}

// ------------------------------------------------ weight transpose fp32->bf16
// W: K x N (row major) -> Wt: N x K bf16.
// PERM=0: identity rows. PERM=1: row n -> (n&15)*64 + (n>>4)  (head-major).
// PERM=2: same permutation applied within each 1024-column half (for W_kv).
template <int PERM>
__global__ __launch_bounds__(256) void transpose_bf16(
    const float* __restrict__ W, bf16* __restrict__ Wt, int K, int N) {
  __shared__ float t[32][33];
  const int n0 = blockIdx.x * 32, k0 = blockIdx.y * 32;
  const int tx = threadIdx.x & 31, ty = threadIdx.x >> 5;
  #pragma unroll
  for (int i = ty; i < 32; i += 8) t[i][tx] = W[(size_t)(k0 + i) * N + n0 + tx];
  __syncthreads();
  #pragma unroll
  for (int i = ty; i < 32; i += 8) {
    int n = n0 + i;
    int np;
    if constexpr (PERM == 0) np = n;
    else if constexpr (PERM == 1) np = (n & 15) * 64 + (n >> 4);
    else { int base = n & 1024, m = n & 1023; np = base + (m & 15) * 64 + (m >> 4); }
    Wt[(size_t)np * K + k0 + tx] = __float2bfloat16(t[tx][i]);
  }
}

// ------------------------------------------------ y -> bf16 (padded to 2560 rows)
__global__ __launch_bounds__(256) void conv_y(
    const float* __restrict__ y, bf16* __restrict__ yb) {
  int i = blockIdx.x * 256 + threadIdx.x;          // < 2560*1024
  float v = (i < 2464 * 1024) ? y[i] : 0.f;
  yb[i] = __float2bfloat16(v);
}

// ------------------------------------------------ ada = silu(noise) @ W_ada + b
__global__ __launch_bounds__(256) void ada_kernel(
    const float* __restrict__ noise, const float* __restrict__ W,
    const float* __restrict__ bias, float* __restrict__ ada) {
  __shared__ float s[16 * 1024];                   // 64 KB
  const int tid = threadIdx.x;
  const int b0 = blockIdx.y * 16;
  for (int i = tid; i < 16 * 1024; i += 256) {
    float v = noise[b0 * 1024 + i];
    s[i] = v / (1.f + __expf(-v));
  }
  __syncthreads();
  const int n = blockIdx.x * 256 + tid;
  float acc[16];
  #pragma unroll
  for (int i = 0; i < 16; ++i) acc[i] = 0.f;
  for (int k = 0; k < 1024; ++k) {
    float w = W[(size_t)k * 6144 + n];
    #pragma unroll
    for (int i = 0; i < 16; ++i) acc[i] += s[i * 1024 + k] * w;
  }
  float bn = bias[n];
  #pragma unroll
  for (int i = 0; i < 16; ++i) ada[(size_t)(b0 + i) * 6144 + n] = acc[i] + bn;
}

// ------------------------------------------------ LN + modulate -> bf16
__global__ __launch_bounds__(256) void ln_mod(
    const float* __restrict__ x, const float* __restrict__ ada,
    int shOff, int scOff, bf16* __restrict__ out) {
  const int row = blockIdx.x, b = row >> 8, tid = threadIdx.x;
  const float* xr = x + (size_t)row * 1024;
  float v[4], s = 0.f, ss = 0.f;
  #pragma unroll
  for (int i = 0; i < 4; ++i) {
    v[i] = xr[tid + i * 256];
    s += v[i]; ss += v[i] * v[i];
  }
  #pragma unroll
  for (int o = 32; o; o >>= 1) { s += __shfl_xor(s, o); ss += __shfl_xor(ss, o); }
  __shared__ float red[8];
  const int w = tid >> 6;
  if ((tid & 63) == 0) { red[w] = s; red[w + 4] = ss; }
  __syncthreads();
  s = red[0] + red[1] + red[2] + red[3];
  ss = red[4] + red[5] + red[6] + red[7];
  float mu = s * (1.f / 1024.f);
  float var = ss * (1.f / 1024.f) - mu * mu;
  float rstd = rsqrtf(var + 1e-6f);
  const float* adab = ada + (size_t)b * 6144;
  #pragma unroll
  for (int i = 0; i < 4; ++i) {
    int c = tid + i * 256;
    float o = (v[i] - mu) * rstd * (1.f + adab[scOff + c]) + adab[shOff + c];
    out[(size_t)row * 1024 + c] = __float2bfloat16(o);
  }
}

// ------------------------------------------------ generic bf16 MFMA GEMM
// C[M,N] = A[M,K] @ Bt[N,K]^T ; 128x128 tile, BK=64, 4 waves (64x64 each)
enum { EPI_STORE = 0, EPI_GELU = 1, EPI_PROJ = 2, EPI_OUT = 3 };

template <int EPI>
__global__ __launch_bounds__(256, 2) void gemm_bf16(
    const bf16* __restrict__ A, const bf16* __restrict__ Bt,
    int M, int N, int K,
    const float* __restrict__ bias, const float* __restrict__ ada, int adaOff,
    const float* __restrict__ resid, float* __restrict__ outF,
    bf16* __restrict__ outB) {
  (void)M;
  __shared__ bf16 As[128 * 64];
  __shared__ bf16 Bs[128 * 64];
  const int tid = threadIdx.x;
  const int w = tid >> 6, lane = tid & 63;
  const int wr = w >> 1, wc = w & 1;
  const int lr = lane >> 4, lc = lane & 15;
  const int mBase = blockIdx.y * 128, nBase = blockIdx.x * 128;

  f32x4 acc[4][4];
  #pragma unroll
  for (int mi = 0; mi < 4; ++mi)
    #pragma unroll
    for (int ni = 0; ni < 4; ++ni)
      #pragma unroll
      for (int j = 0; j < 4; ++j) acc[mi][ni][j] = 0.f;

  const int nK = K >> 6;
  for (int ks = 0; ks < nK; ++ks) {
    const int k0 = ks << 6;
    #pragma unroll
    for (int i = 0; i < 4; ++i) {
      int t16 = w * 256 + i * 64 + lane;           // 16B chunk id 0..1023
      int row = t16 >> 3;                          // tile row 0..127
      int cL = ((t16 & 7) ^ (row & 7)) << 3;       // swizzled elem offset in row
      gload_lds16(A + (size_t)(mBase + row) * K + k0 + cL, (char*)As + t16 * 16);
      gload_lds16(Bt + (size_t)(nBase + row) * K + k0 + cL, (char*)Bs + t16 * 16);
    }
    __syncthreads();
    #pragma unroll
    for (int kk = 0; kk < 2; ++kk) {
      bf16x8 af[4], bfr[4];
      #pragma unroll
      for (int mi = 0; mi < 4; ++mi) {
        int row = wr * 64 + mi * 16 + lc;
        int byte = row * 128 + ((kk * 64 + lr * 16) ^ ((row & 7) << 4));
        af[mi] = *reinterpret_cast<const bf16x8*>((const char*)As + byte);
      }
      #pragma unroll
      for (int ni = 0; ni < 4; ++ni) {
        int row = wc * 64 + ni * 16 + lc;
        int byte = row * 128 + ((kk * 64 + lr * 16) ^ ((row & 7) << 4));
        bfr[ni] = *reinterpret_cast<const bf16x8*>((const char*)Bs + byte);
      }
      #pragma unroll
      for (int mi = 0; mi < 4; ++mi)
        #pragma unroll
        for (int ni = 0; ni < 4; ++ni)
          acc[mi][ni] = __builtin_amdgcn_mfma_f32_16x16x32_bf16(
              af[mi], bfr[ni], acc[mi][ni], 0, 0, 0);
    }
    __syncthreads();
  }

  const int rB = mBase + wr * 64, cB = nBase + wc * 64;
  #pragma unroll
  for (int mi = 0; mi < 4; ++mi) {
    #pragma unroll
    for (int ni = 0; ni < 4; ++ni) {
      #pragma unroll
      for (int j = 0; j < 4; ++j) {
        int r = rB + mi * 16 + lr * 4 + j;
        int c = cB + ni * 16 + lc;
        float v = acc[mi][ni][j];
        if (bias) v += bias[c];
        if constexpr (EPI == EPI_STORE) {
          outB[(size_t)r * N + c] = __float2bfloat16(v);
        } else if constexpr (EPI == EPI_GELU) {
          float e = __expf(1.5957691216057308f * v + 0.07135481627260086f * v * v * v);
          float t = 1.f - 2.f / (e + 1.f);         // tanh, overflow-safe
          outB[(size_t)r * N + c] = __float2bfloat16(0.5f * v * (1.f + t));
        } else if constexpr (EPI == EPI_PROJ) {
          int b = r >> 8;
          float g = ada[(size_t)b * 6144 + adaOff + c];
          float o = resid[(size_t)r * 1024 + c] + g * v;
          outF[(size_t)r * 1024 + c] = o;
          outB[(size_t)r * 1024 + c] = __float2bfloat16(o);
        } else {  // EPI_OUT
          int b = r >> 8;
          float g = ada[(size_t)b * 6144 + adaOff + c];
          outF[(size_t)r * 1024 + c] = resid[(size_t)r * 1024 + c] + g * v;
        }
      }
    }
  }
}

// ------------------------------------------------ window attention (attn1, MFMA)
// block = (b,h), 8 waves x 32 q-rows; flash over 8 key-tiles of 32.
// qkv layout: [b][n][3][h][dh], row stride 3072.
__global__ __launch_bounds__(512, 1) void attn1_mfma(
    const bf16* __restrict__ qkv, const float* __restrict__ rel,
    bf16* __restrict__ o) {
  __shared__ bf16 Ks[256 * 64];          // rows XOR-swizzled in 16B chunks
  __shared__ bf16 Vt[64 * 256];          // V transposed [dh][key], XOR-swizzled
  __shared__ ushort Pl[8][32 * 40];      // per-wave P (bf16 bits), stride 40
  __shared__ float bias_s[964];

  const int tid = threadIdx.x;
  const int w = tid >> 6, lane = tid & 63;
  const int p4 = lane >> 4, c = lane & 15;
  const int bh = blockIdx.x, b = bh >> 4, h = bh & 15;
  const bf16* basep = qkv + (size_t)b * 256 * 3072 + h * 64;

  #pragma unroll
  for (int it = 0; it < 4; ++it) {
    int t16 = it * 512 + tid;                       // 0..2047
    int row = t16 >> 3;
    int sc = ((t16 & 7) ^ (row & 7)) << 3;
    gload_lds16(basep + (size_t)row * 3072 + 1024 + sc, (char*)Ks + t16 * 16);
  }
  #pragma unroll
  for (int it = 0; it < 4; ++it) {
    int i = it * 512 + tid;                         // chunk id 0..2047
    int key = i >> 3, d0 = (i & 7) * 8;
    int4 u = *reinterpret_cast<const int4*>(basep + (size_t)key * 3072 + 2048 + d0);
    const ushort* us = reinterpret_cast<const ushort*>(&u);
    #pragma unroll
    for (int j = 0; j < 8; ++j) {
      int dh = d0 + j;
      int byte = dh * 512 + ((key * 2) ^ ((dh & 7) << 4));
      *reinterpret_cast<ushort*>((char*)Vt + byte) = us[j];
    }
  }
  for (int i = tid; i < 964; i += 512) bias_s[i] = rel[i * 16 + h];

  bf16x8 qf[2][2];
  #pragma unroll
  for (int mi = 0; mi < 2; ++mi)
    #pragma unroll
    for (int s = 0; s < 2; ++s) {
      int q = w * 32 + mi * 16 + c;
      int dh = s * 32 + p4 * 8;
      int4 u = *reinterpret_cast<const int4*>(basep + (size_t)q * 3072 + dh);
      uint32_t a[4] = {(uint32_t)u.x, (uint32_t)u.y, (uint32_t)u.z, (uint32_t)u.w};
      bf16x8 r;
      #pragma unroll
      for (int t = 0; t < 4; ++t) {
        float lo = __uint_as_float(a[t] << 16) * 0.125f;
        float hi = __uint_as_float(a[t] & 0xffff0000u) * 0.125f;
        r[2 * t]     = (short)(__float_as_uint(lo) >> 16);   // exact
        r[2 * t + 1] = (short)(__float_as_uint(hi) >> 16);
      }
      qf[mi][s] = r;
    }
  __syncthreads();

  float m_run[2][4], l_run[2][4];
  f32x4 oacc[2][4];
  #pragma unroll
  for (int mi = 0; mi < 2; ++mi)
    #pragma unroll
    for (int j = 0; j < 4; ++j) {
      m_run[mi][j] = -1e30f; l_run[mi][j] = 0.f;
      oacc[mi][j] = f32x4{0.f, 0.f, 0.f, 0.f};
    }

  ushort* Pw = &Pl[w][0];
  const int colterm = p4 * 4 - c + 15;

  for (int kt = 0; kt < 8; ++kt) {
    f32x4 sacc[2][2];
    #pragma unroll
    for (int mi = 0; mi < 2; ++mi)
      #pragma unroll
      for (int nf = 0; nf < 2; ++nf) {
        int bi = ((w * 2 + mi) - (kt * 2 + nf) + 15) * 31 + colterm;
        #pragma unroll
        for (int j = 0; j < 4; ++j) sacc[mi][nf][j] = bias_s[bi + j];
      }
    #pragma unroll
    for (int nf = 0; nf < 2; ++nf) {
      int key = kt * 32 + nf * 16 + c;
      #pragma unroll
      for (int s = 0; s < 2; ++s) {
        int byte = key * 128 + (((s * 4 + p4) ^ (key & 7)) << 4);
        bf16x8 kb = *reinterpret_cast<const bf16x8*>((const char*)Ks + byte);
        #pragma unroll
        for (int mi = 0; mi < 2; ++mi)
          sacc[mi][nf] = __builtin_amdgcn_mfma_f32_16x16x32_bf16(
              qf[mi][s], kb, sacc[mi][nf], 0, 0, 0);
      }
    }
    float sf[2][4];
    #pragma unroll
    for (int mi = 0; mi < 2; ++mi)
      #pragma unroll
      for (int j = 0; j < 4; ++j) {
        float cm = fmaxf(sacc[mi][0][j], sacc[mi][1][j]);
        cm = fmaxf(cm, __shfl_xor(cm, 1));
        cm = fmaxf(cm, __shfl_xor(cm, 2));
        cm = fmaxf(cm, __shfl_xor(cm, 4));
        cm = fmaxf(cm, __shfl_xor(cm, 8));
        float nm = fmaxf(m_run[mi][j], cm);
        sf[mi][j] = __expf(m_run[mi][j] - nm);
        m_run[mi][j] = nm;
        l_run[mi][j] *= sf[mi][j];
      }
    #pragma unroll
    for (int mi = 0; mi < 2; ++mi)
      #pragma unroll
      for (int nf = 0; nf < 4; ++nf)
        #pragma unroll
        for (int j = 0; j < 4; ++j) oacc[mi][nf][j] *= sf[mi][j];
    #pragma unroll
    for (int mi = 0; mi < 2; ++mi) {
      #pragma unroll
      for (int nf = 0; nf < 2; ++nf)
        #pragma unroll
        for (int j = 0; j < 4; ++j)
          sacc[mi][nf][j] = __expf(sacc[mi][nf][j] - m_run[mi][j]);
      #pragma unroll
      for (int j = 0; j < 4; ++j) {
        float lp = sacc[mi][0][j] + sacc[mi][1][j];
        lp += __shfl_xor(lp, 1);
        lp += __shfl_xor(lp, 2);
        lp += __shfl_xor(lp, 4);
        lp += __shfl_xor(lp, 8);
        l_run[mi][j] += lp;
      }
      #pragma unroll
      for (int nf = 0; nf < 2; ++nf)
        #pragma unroll
        for (int j = 0; j < 4; ++j)
          Pw[(mi * 16 + p4 * 4 + j) * 40 + nf * 16 + c] =
              f2bf_bits(sacc[mi][nf][j]);
    }
    bf16x8 pa[2], vb[4];
    #pragma unroll
    for (int mi = 0; mi < 2; ++mi)
      pa[mi] = *reinterpret_cast<const bf16x8*>(
          (const char*)Pw + (mi * 16 + c) * 80 + p4 * 16);
    #pragma unroll
    for (int nf = 0; nf < 4; ++nf) {
      int dh = nf * 16 + c;
      int byte = dh * 512 + (((kt * 4 + p4) ^ (dh & 7)) << 4);
      vb[nf] = *reinterpret_cast<const bf16x8*>((const char*)Vt + byte);
    }
    #pragma unroll
    for (int mi = 0; mi < 2; ++mi)
      #pragma unroll
      for (int nf = 0; nf < 4; ++nf)
        oacc[mi][nf] = __builtin_amdgcn_mfma_f32_16x16x32_bf16(
            pa[mi], vb[nf], oacc[mi][nf], 0, 0, 0);
  }

  #pragma unroll
  for (int mi = 0; mi < 2; ++mi) {
    float inv[4];
    #pragma unroll
    for (int j = 0; j < 4; ++j) inv[j] = 1.f / l_run[mi][j];
    #pragma unroll
    for (int nf = 0; nf < 4; ++nf)
      #pragma unroll
      for (int j = 0; j < 4; ++j) {
        int q = w * 32 + mi * 16 + p4 * 4 + j;
        int dh = nf * 16 + c;
        o[((size_t)b * 256 + q) * 1024 + h * 64 + dh] =
            __float2bfloat16(oacc[mi][nf][j] * inv[j]);
      }
  }
}

// ------------------------------------------------ cross attention (attn2, MFMA)
// Inputs now head-major: q2[b][n][h*64+d], kv[b][m][h*64+d] (+1024 for v).
// block = (b,h), 8 waves x 32 q-rows, all 77 keys (padded to 80, masked).
// Output o2[b][n][h*64+d] bf16 (coalesced); permute_add folds into xcur.
__global__ __launch_bounds__(512, 1) void attn2_mfma(
    const bf16* __restrict__ q2, const bf16* __restrict__ kv,
    bf16* __restrict__ o2) {
  __shared__ bf16 Ks[80 * 64];            // swizzled rows (128B each), 10 KB
  __shared__ bf16 Vt[64 * 128];           // [dh][key], 256B rows, 16 KB
  __shared__ ushort Pl[8][32 * 104];      // P bf16, stride 104 elems, 52 KB

  const int tid = threadIdx.x;
  const int w = tid >> 6, lane = tid & 63;
  const int p4 = lane >> 4, c = lane & 15;
  const int bh = blockIdx.x, b = bh >> 4, h = bh & 15;
  const size_t kvrow0 = (size_t)b * 77;

  // stage K (keys 0..79; 77..79 masked later), pre-swizzled source
  {
    int t16 = tid;                                  // 0..511
    int key = t16 >> 3;
    int sc = ((t16 & 7) ^ (key & 7)) << 3;
    gload_lds16(kv + (kvrow0 + key) * 2048 + h * 64 + sc, (char*)Ks + t16 * 16);
    if (tid < 128) {
      int u16 = 512 + tid; key = u16 >> 3;
      sc = ((u16 & 7) ^ (key & 7)) << 3;
      gload_lds16(kv + (kvrow0 + key) * 2048 + h * 64 + sc, (char*)Ks + u16 * 16);
    }
  }
  // stage V transposed, XOR swizzle on key 16B-chunks
  for (int i = tid; i < 80 * 8; i += 512) {
    int key = i >> 3, d0 = (i & 7) * 8;
    int4 u = *reinterpret_cast<const int4*>(
        kv + (kvrow0 + key) * 2048 + 1024 + h * 64 + d0);
    const ushort* us = reinterpret_cast<const ushort*>(&u);
    #pragma unroll
    for (int j = 0; j < 8; ++j) {
      int dh = d0 + j;
      int byte = dh * 256 + ((key * 2) ^ ((dh & 7) << 4));
      *reinterpret_cast<ushort*>((char*)Vt + byte) = us[j];
    }
  }
  // zero P cols 80..95 for this wave (PV K-padding reads zeros)
  {
    int row = lane >> 1, colb = 160 + (lane & 1) * 16;
    *reinterpret_cast<int4*>((char*)&Pl[w][0] + row * 208 + colb) =
        int4{0, 0, 0, 0};
  }
  // Q frags, pre-scaled by 0.125
  bf16x8 qf[2][2];
  #pragma unroll
  for (int mi = 0; mi < 2; ++mi)
    #pragma unroll
    for (int s = 0; s < 2; ++s) {
      int q = w * 32 + mi * 16 + c;
      int dh = s * 32 + p4 * 8;
      int4 u = *reinterpret_cast<const int4*>(
          q2 + ((size_t)b * 256 + q) * 1024 + h * 64 + dh);
      uint32_t a[4] = {(uint32_t)u.x, (uint32_t)u.y, (uint32_t)u.z, (uint32_t)u.w};
      bf16x8 r;
      #pragma unroll
      for (int t = 0; t < 4; ++t) {
        float lo = __uint_as_float(a[t] << 16) * 0.125f;
        float hi = __uint_as_float(a[t] & 0xffff0000u) * 0.125f;
        r[2 * t]     = (short)(__float_as_uint(lo) >> 16);
        r[2 * t + 1] = (short)(__float_as_uint(hi) >> 16);
      }
      qf[mi][s] = r;
    }
  __syncthreads();

  // QK^T over 5 key-tiles of 16
  f32x4 sacc[2][5];
  #pragma unroll
  for (int mi = 0; mi < 2; ++mi)
    #pragma unroll
    for (int nf = 0; nf < 5; ++nf)
      sacc[mi][nf] = f32x4{0.f, 0.f, 0.f, 0.f};
  #pragma unroll
  for (int nf = 0; nf < 5; ++nf) {
    int key = nf * 16 + c;
    #pragma unroll
    for (int s = 0; s < 2; ++s) {
      int byte = key * 128 + (((s * 4 + p4) ^ (key & 7)) << 4);
      bf16x8 kb = *reinterpret_cast<const bf16x8*>((const char*)Ks + byte);
      #pragma unroll
      for (int mi = 0; mi < 2; ++mi)
        sacc[mi][nf] = __builtin_amdgcn_mfma_f32_16x16x32_bf16(
            qf[mi][s], kb, sacc[mi][nf], 0, 0, 0);
    }
  }
  // mask keys 77..79
  if (c >= 13) {
    #pragma unroll
    for (int mi = 0; mi < 2; ++mi)
      #pragma unroll
      for (int j = 0; j < 4; ++j) sacc[mi][4][j] = -1e30f;
  }
  // full softmax (no online pass needed: all keys resident)
  float lrow[2][4];
  #pragma unroll
  for (int mi = 0; mi < 2; ++mi)
    #pragma unroll
    for (int j = 0; j < 4; ++j) {
      float cm = sacc[mi][0][j];
      #pragma unroll
      for (int nf = 1; nf < 5; ++nf) cm = fmaxf(cm, sacc[mi][nf][j]);
      cm = fmaxf(cm, __shfl_xor(cm, 1));
      cm = fmaxf(cm, __shfl_xor(cm, 2));
      cm = fmaxf(cm, __shfl_xor(cm, 4));
      cm = fmaxf(cm, __shfl_xor(cm, 8));
      float lp = 0.f;
      #pragma unroll
      for (int nf = 0; nf < 5; ++nf) {
        sacc[mi][nf][j] = __expf(sacc[mi][nf][j] - cm);
        lp += sacc[mi][nf][j];
      }
      lp += __shfl_xor(lp, 1);
      lp += __shfl_xor(lp, 2);
      lp += __shfl_xor(lp, 4);
      lp += __shfl_xor(lp, 8);
      lrow[mi][j] = lp;
    }
  // pack P to LDS (bf16)
  ushort* Pw = &Pl[w][0];
  #pragma unroll
  for (int mi = 0; mi < 2; ++mi)
    #pragma unroll
    for (int nf = 0; nf < 5; ++nf)
      #pragma unroll
      for (int j = 0; j < 4; ++j)
        Pw[(mi * 16 + p4 * 4 + j) * 104 + nf * 16 + c] =
            f2bf_bits(sacc[mi][nf][j]);
  // PV: K = 96 (cols 80..95 are zeros)
  f32x4 oacc[2][4];
  #pragma unroll
  for (int mi = 0; mi < 2; ++mi)
    #pragma unroll
    for (int nf = 0; nf < 4; ++nf) oacc[mi][nf] = f32x4{0.f, 0.f, 0.f, 0.f};
  #pragma unroll
  for (int kk = 0; kk < 3; ++kk) {
    bf16x8 pa[2], vb[4];
    #pragma unroll
    for (int mi = 0; mi < 2; ++mi)
      pa[mi] = *reinterpret_cast<const bf16x8*>(
          (const char*)Pw + (mi * 16 + c) * 208 + kk * 64 + p4 * 16);
    #pragma unroll
    for (int nf = 0; nf < 4; ++nf) {
      int dh = nf * 16 + c;
      int byte = dh * 256 + (((kk * 4 + p4) ^ (dh & 7)) << 4);
      vb[nf] = *reinterpret_cast<const bf16x8*>((const char*)Vt + byte);
    }
    #pragma unroll
    for (int mi = 0; mi < 2; ++mi)
      #pragma unroll
      for (int nf = 0; nf < 4; ++nf)
        oacc[mi][nf] = __builtin_amdgcn_mfma_f32_16x16x32_bf16(
            pa[mi], vb[nf], oacc[mi][nf], 0, 0, 0);
  }
  // store o2 head-major (coalesced)
  #pragma unroll
  for (int mi = 0; mi < 2; ++mi) {
    float inv[4];
    #pragma unroll
    for (int j = 0; j < 4; ++j) inv[j] = 1.f / lrow[mi][j];
    #pragma unroll
    for (int nf = 0; nf < 4; ++nf)
      #pragma unroll
      for (int j = 0; j < 4; ++j) {
        int q = w * 32 + mi * 16 + p4 * 4 + j;
        int dh = nf * 16 + c;
        o2[((size_t)b * 256 + q) * 1024 + h * 64 + dh] =
            __float2bfloat16(oacc[mi][nf][j] * inv[j]);
      }
  }
}

// ------------------------------------------------ o2 head-major -> xcur += (d*16+h)
// Stage row in skewed LDS (addr = s + s>>4 : 2-way banks max), coalesced RMW.
__global__ __launch_bounds__(256) void permute_add(
    const bf16* __restrict__ o2, float* __restrict__ xcur) {
  __shared__ float s_lds[1088];
  const int tid = threadIdx.x;
  const int row0 = blockIdx.x * 4;
  for (int r = 0; r < 4; ++r) {
    const int row = row0 + r;
    #pragma unroll
    for (int i = 0; i < 4; ++i) {
      int cc = i * 256 + tid;
      float v = __bfloat162float(o2[(size_t)row * 1024 + cc]);
      s_lds[cc + (cc >> 4)] = v;
    }
    __syncthreads();
    float4 add;
    #pragma unroll
    for (int t = 0; t < 4; ++t) {
      int ct = tid * 4 + t;
      int src = (ct & 15) * 64 + (ct >> 4);
      (&add.x)[t] = s_lds[src + (src >> 4)];
    }
    float4* xp = reinterpret_cast<float4*>(xcur + (size_t)row * 1024 + tid * 4);
    float4 cur = *xp;
    cur.x += add.x; cur.y += add.y; cur.z += add.z; cur.w += add.w;
    *xp = cur;
    __syncthreads();
  }
}

// ---------------------------------------------------------------- launcher

extern "C" void kernel_launch(void* const* d_in, const int* in_sizes, int n_in,
                              void* d_out, int out_size, void* d_ws, size_t ws_size,
                              hipStream_t stream) {
  (void)in_sizes; (void)n_in; (void)out_size; (void)ws_size;
  const float* x      = (const float*)d_in[0];
  const float* noise  = (const float*)d_in[1];
  const float* y      = (const float*)d_in[2];
  const float* W_qkv  = (const float*)d_in[3];
  const float* b_qkv  = (const float*)d_in[4];
  const float* W_proj = (const float*)d_in[5];
  const float* b_proj = (const float*)d_in[6];
  const float* rel    = (const float*)d_in[7];
  const float* W_ada  = (const float*)d_in[8];
  const float* b_ada  = (const float*)d_in[9];
  const float* W_fc1  = (const float*)d_in[10];
  const float* b_fc1  = (const float*)d_in[11];
  const float* W_fc2  = (const float*)d_in[12];
  const float* b_fc2  = (const float*)d_in[13];
  const float* W_q    = (const float*)d_in[14];
  const float* W_kv   = (const float*)d_in[15];

  char* ws = (char*)d_ws;
  size_t off = 0;
  auto alloc = [&](size_t bytes) {
    char* p = ws + off;
    off = (off + bytes + 255) & ~(size_t)255;
    return p;
  };
  float* ada   = (float*)alloc(32u * 6144 * 4);
  float* xcur  = (float*)alloc(8192u * 1024 * 4);
  bf16* WqkvT  = (bf16*)alloc(3072u * 1024 * 2);
  bf16* WprojT = (bf16*)alloc(1024u * 1024 * 2);
  bf16* WqT    = (bf16*)alloc(1024u * 1024 * 2);
  bf16* WkvT   = (bf16*)alloc(2048u * 1024 * 2);
  bf16* Wfc1T  = (bf16*)alloc(4096u * 1024 * 2);
  bf16* Wfc2T  = (bf16*)alloc(1024u * 4096 * 2);
  bf16* hbuf   = (bf16*)alloc(8192u * 1024 * 2);
  bf16* big    = (bf16*)alloc(8192u * 4096 * 2);   // qkv / o2 / mlp-h
  bf16* obuf   = (bf16*)alloc(8192u * 1024 * 2);   // attn1 o, then q2
  bf16* kvbuf  = (bf16*)alloc(2560u * 2048 * 2);
  bf16* ybuf   = (bf16*)alloc(2560u * 1024 * 2);
  float* outF  = (float*)d_out;

  // weight prep (W_q / W_kv get head-major column permutation)
  transpose_bf16<0><<<dim3(96, 32), 256, 0, stream>>>(W_qkv, WqkvT, 1024, 3072);
  transpose_bf16<0><<<dim3(32, 32), 256, 0, stream>>>(W_proj, WprojT, 1024, 1024);
  transpose_bf16<1><<<dim3(32, 32), 256, 0, stream>>>(W_q, WqT, 1024, 1024);
  transpose_bf16<2><<<dim3(64, 32), 256, 0, stream>>>(W_kv, WkvT, 1024, 2048);
  transpose_bf16<0><<<dim3(128, 32), 256, 0, stream>>>(W_fc1, Wfc1T, 1024, 4096);
  transpose_bf16<0><<<dim3(32, 128), 256, 0, stream>>>(W_fc2, Wfc2T, 4096, 1024);
  conv_y<<<2560 * 1024 / 256, 256, 0, stream>>>(y, ybuf);
  ada_kernel<<<dim3(24, 2), 256, 0, stream>>>(noise, W_ada, b_ada, ada);

  // MSA branch
  ln_mod<<<8192, 256, 0, stream>>>(x, ada, 0, 1024, hbuf);
  gemm_bf16<EPI_STORE><<<dim3(24, 64), 256, 0, stream>>>(
      hbuf, WqkvT, 8192, 3072, 1024, b_qkv, nullptr, 0, nullptr, nullptr, big);
  attn1_mfma<<<512, 512, 0, stream>>>(big, rel, obuf);
  gemm_bf16<EPI_PROJ><<<dim3(8, 64), 256, 0, stream>>>(
      obuf, WprojT, 8192, 1024, 1024, b_proj, ada, 2048, x, xcur, hbuf);

  // cross-attention branch (head-major q2/kv)
  gemm_bf16<EPI_STORE><<<dim3(8, 64), 256, 0, stream>>>(
      hbuf, WqT, 8192, 1024, 1024, nullptr, nullptr, 0, nullptr, nullptr, obuf);
  gemm_bf16<EPI_STORE><<<dim3(16, 20), 256, 0, stream>>>(
      ybuf, WkvT, 2560, 2048, 1024, nullptr, nullptr, 0, nullptr, nullptr, kvbuf);
  attn2_mfma<<<512, 512, 0, stream>>>(obuf, kvbuf, big);
  permute_add<<<2048, 256, 0, stream>>>(big, xcur);

  // MLP branch
  ln_mod<<<8192, 256, 0, stream>>>(xcur, ada, 3072, 4096, hbuf);
  gemm_bf16<EPI_GELU><<<dim3(32, 64), 256, 0, stream>>>(
      hbuf, Wfc1T, 8192, 4096, 1024, b_fc1, nullptr, 0, nullptr, nullptr, big);
  gemm_bf16<EPI_OUT><<<dim3(8, 64), 256, 0, stream>>>(
      big, Wfc2T, 8192, 1024, 4096, b_fc2, ada, 5120, xcur, outF, nullptr);
}

// Round 5
// 575.244 us; speedup vs baseline: 2.3604x; 1.1816x over previous
//
#include <hip/hip_runtime.h>
#include <hip/hip_bf16.h>
#include <stdint.h>

typedef __hip_bfloat16 bf16;
using bf16x8 = __attribute__((ext_vector_type(8))) short;   // 8 bf16 (4 VGPRs)
using f32x4  = __attribute__((ext_vector_type(4))) float;   // 4 fp32

// ---------------------------------------------------------------- utilities

__device__ __forceinline__ void gload_lds16(const void* g, void* l) {
  using gchar = __attribute__((address_space(1))) char;
  using lchar = __attribute__((address_space(3))) char;
  gchar* gp = reinterpret_cast<gchar*>(reinterpret_cast<uintptr_t>(g));
  lchar* lp = reinterpret_cast<lchar*>(static_cast<uint32_t>(reinterpret_cast<uintptr_t>(l)));
  __builtin_amdgcn_global_load_lds(gp, lp, 16, 0, 0);
}

__device__ __forceinline__ unsigned short f2bf_bits(float x) {
  uint32_t u = __float_as_uint(x);
  uint32_t r = (u + 0x7fffu + ((u >> 16) & 1u)) >> 16;
  return (unsigned short)r;
}

// ------------------------------------------------ weight transpose fp32->bf16
// W: K x N (row major) -> Wt: N x K bf16.
// PERM=0: identity rows. PERM=1: row n -> (n&15)*64 + (n>>4)  (head-major).
// PERM=2: same permutation applied within each 1024-column half (for W_kv).
template <int PERM>
__global__ __launch_bounds__(256) void transpose_bf16(
    const float* __restrict__ W, bf16* __restrict__ Wt, int K, int N) {
  __shared__ float t[32][33];
  const int n0 = blockIdx.x * 32, k0 = blockIdx.y * 32;
  const int tx = threadIdx.x & 31, ty = threadIdx.x >> 5;
  #pragma unroll
  for (int i = ty; i < 32; i += 8) t[i][tx] = W[(size_t)(k0 + i) * N + n0 + tx];
  __syncthreads();
  #pragma unroll
  for (int i = ty; i < 32; i += 8) {
    int n = n0 + i;
    int np;
    if constexpr (PERM == 0) np = n;
    else if constexpr (PERM == 1) np = (n & 15) * 64 + (n >> 4);
    else { int base = n & 1024, m = n & 1023; np = base + (m & 15) * 64 + (m >> 4); }
    Wt[(size_t)np * K + k0 + tx] = __float2bfloat16(t[tx][i]);
  }
}

// ------------------------------------------------ y -> bf16 (padded to 2560 rows)
__global__ __launch_bounds__(256) void conv_y(
    const float* __restrict__ y, bf16* __restrict__ yb) {
  int i = blockIdx.x * 256 + threadIdx.x;          // < 2560*1024
  float v = (i < 2464 * 1024) ? y[i] : 0.f;
  yb[i] = __float2bfloat16(v);
}

// ------------------------------------------------ silu(noise) -> bf16, pad to 128 rows
__global__ __launch_bounds__(256) void silu_pad(
    const float* __restrict__ noise, bf16* __restrict__ Apad) {
  int i = blockIdx.x * 256 + threadIdx.x;          // over 128*1024
  float v = 0.f;
  if (i < 32 * 1024) {
    float x = noise[i];
    v = x / (1.f + __expf(-x));
  }
  Apad[i] = __float2bfloat16(v);
}

// ------------------------------------------------ LN + modulate -> bf16
__global__ __launch_bounds__(256) void ln_mod(
    const float* __restrict__ x, const float* __restrict__ ada,
    int shOff, int scOff, bf16* __restrict__ out) {
  const int row = blockIdx.x, b = row >> 8, tid = threadIdx.x;
  const float* xr = x + (size_t)row * 1024;
  float v[4], s = 0.f, ss = 0.f;
  #pragma unroll
  for (int i = 0; i < 4; ++i) {
    v[i] = xr[tid + i * 256];
    s += v[i]; ss += v[i] * v[i];
  }
  #pragma unroll
  for (int o = 32; o; o >>= 1) { s += __shfl_xor(s, o); ss += __shfl_xor(ss, o); }
  __shared__ float red[8];
  const int w = tid >> 6;
  if ((tid & 63) == 0) { red[w] = s; red[w + 4] = ss; }
  __syncthreads();
  s = red[0] + red[1] + red[2] + red[3];
  ss = red[4] + red[5] + red[6] + red[7];
  float mu = s * (1.f / 1024.f);
  float var = ss * (1.f / 1024.f) - mu * mu;
  float rstd = rsqrtf(var + 1e-6f);
  const float* adab = ada + (size_t)b * 6144;
  #pragma unroll
  for (int i = 0; i < 4; ++i) {
    int c = tid + i * 256;
    float o = (v[i] - mu) * rstd * (1.f + adab[scOff + c]) + adab[shOff + c];
    out[(size_t)row * 1024 + c] = __float2bfloat16(o);
  }
}

// ------------------------------------------------ generic bf16 MFMA GEMM
// C[M,N] = A[M,K] @ Bt[N,K]^T ; 128x128 tile, BK=64, 4 waves (64x64 each)
enum { EPI_STORE = 0, EPI_GELU = 1, EPI_PROJ = 2, EPI_OUT = 3, EPI_ADAF = 4 };

template <int EPI>
__global__ __launch_bounds__(256, 2) void gemm_bf16(
    const bf16* __restrict__ A, const bf16* __restrict__ Bt,
    int M, int N, int K,
    const float* __restrict__ bias, const float* __restrict__ ada, int adaOff,
    const float* __restrict__ resid, float* __restrict__ outF,
    bf16* __restrict__ outB) {
  (void)M;
  __shared__ bf16 As[128 * 64];
  __shared__ bf16 Bs[128 * 64];
  const int tid = threadIdx.x;
  const int w = tid >> 6, lane = tid & 63;
  const int wr = w >> 1, wc = w & 1;
  const int lr = lane >> 4, lc = lane & 15;
  const int mBase = blockIdx.y * 128, nBase = blockIdx.x * 128;

  f32x4 acc[4][4];
  #pragma unroll
  for (int mi = 0; mi < 4; ++mi)
    #pragma unroll
    for (int ni = 0; ni < 4; ++ni)
      #pragma unroll
      for (int j = 0; j < 4; ++j) acc[mi][ni][j] = 0.f;

  const int nK = K >> 6;
  for (int ks = 0; ks < nK; ++ks) {
    const int k0 = ks << 6;
    #pragma unroll
    for (int i = 0; i < 4; ++i) {
      int t16 = w * 256 + i * 64 + lane;           // 16B chunk id 0..1023
      int row = t16 >> 3;                          // tile row 0..127
      int cL = ((t16 & 7) ^ (row & 7)) << 3;       // swizzled elem offset in row
      gload_lds16(A + (size_t)(mBase + row) * K + k0 + cL, (char*)As + t16 * 16);
      gload_lds16(Bt + (size_t)(nBase + row) * K + k0 + cL, (char*)Bs + t16 * 16);
    }
    __syncthreads();
    #pragma unroll
    for (int kk = 0; kk < 2; ++kk) {
      bf16x8 af[4], bfr[4];
      #pragma unroll
      for (int mi = 0; mi < 4; ++mi) {
        int row = wr * 64 + mi * 16 + lc;
        int byte = row * 128 + ((kk * 64 + lr * 16) ^ ((row & 7) << 4));
        af[mi] = *reinterpret_cast<const bf16x8*>((const char*)As + byte);
      }
      #pragma unroll
      for (int ni = 0; ni < 4; ++ni) {
        int row = wc * 64 + ni * 16 + lc;
        int byte = row * 128 + ((kk * 64 + lr * 16) ^ ((row & 7) << 4));
        bfr[ni] = *reinterpret_cast<const bf16x8*>((const char*)Bs + byte);
      }
      #pragma unroll
      for (int mi = 0; mi < 4; ++mi)
        #pragma unroll
        for (int ni = 0; ni < 4; ++ni)
          acc[mi][ni] = __builtin_amdgcn_mfma_f32_16x16x32_bf16(
              af[mi], bfr[ni], acc[mi][ni], 0, 0, 0);
    }
    __syncthreads();
  }

  const int rB = mBase + wr * 64, cB = nBase + wc * 64;
  #pragma unroll
  for (int mi = 0; mi < 4; ++mi) {
    #pragma unroll
    for (int ni = 0; ni < 4; ++ni) {
      #pragma unroll
      for (int j = 0; j < 4; ++j) {
        int r = rB + mi * 16 + lr * 4 + j;
        int c = cB + ni * 16 + lc;
        float v = acc[mi][ni][j];
        if (bias) v += bias[c];
        if constexpr (EPI == EPI_STORE) {
          outB[(size_t)r * N + c] = __float2bfloat16(v);
        } else if constexpr (EPI == EPI_GELU) {
          float e = __expf(1.5957691216057308f * v + 0.07135481627260086f * v * v * v);
          float t = 1.f - 2.f / (e + 1.f);         // tanh, overflow-safe
          outB[(size_t)r * N + c] = __float2bfloat16(0.5f * v * (1.f + t));
        } else if constexpr (EPI == EPI_PROJ) {
          int b = r >> 8;
          float g = ada[(size_t)b * 6144 + adaOff + c];
          float o = resid[(size_t)r * 1024 + c] + g * v;
          outF[(size_t)r * 1024 + c] = o;
          outB[(size_t)r * 1024 + c] = __float2bfloat16(o);
        } else if constexpr (EPI == EPI_OUT) {
          int b = r >> 8;
          float g = ada[(size_t)b * 6144 + adaOff + c];
          outF[(size_t)r * 1024 + c] = resid[(size_t)r * 1024 + c] + g * v;
        } else {  // EPI_ADAF: fp32 store, only real rows (M=32, padded to 128)
          if (r < 32) outF[(size_t)r * N + c] = v;
        }
      }
    }
  }
}

// ------------------------------------------------ window attention (attn1, MFMA)
// block = (b,h), 8 waves x 32 q-rows; flash over 8 key-tiles of 32.
// qkv layout: [b][n][3][h][dh], row stride 3072.
__global__ __launch_bounds__(512, 1) void attn1_mfma(
    const bf16* __restrict__ qkv, const float* __restrict__ rel,
    bf16* __restrict__ o) {
  __shared__ bf16 Ks[256 * 64];          // rows XOR-swizzled in 16B chunks
  __shared__ bf16 Vt[64 * 256];          // V transposed [dh][key], XOR-swizzled
  __shared__ ushort Pl[8][32 * 40];      // per-wave P (bf16 bits), stride 40
  __shared__ float bias_s[964];

  const int tid = threadIdx.x;
  const int w = tid >> 6, lane = tid & 63;
  const int p4 = lane >> 4, c = lane & 15;
  const int bh = blockIdx.x, b = bh >> 4, h = bh & 15;
  const bf16* basep = qkv + (size_t)b * 256 * 3072 + h * 64;

  #pragma unroll
  for (int it = 0; it < 4; ++it) {
    int t16 = it * 512 + tid;                       // 0..2047
    int row = t16 >> 3;
    int sc = ((t16 & 7) ^ (row & 7)) << 3;
    gload_lds16(basep + (size_t)row * 3072 + 1024 + sc, (char*)Ks + t16 * 16);
  }
  #pragma unroll
  for (int it = 0; it < 4; ++it) {
    int i = it * 512 + tid;                         // chunk id 0..2047
    int key = i >> 3, d0 = (i & 7) * 8;
    int4 u = *reinterpret_cast<const int4*>(basep + (size_t)key * 3072 + 2048 + d0);
    const ushort* us = reinterpret_cast<const ushort*>(&u);
    #pragma unroll
    for (int j = 0; j < 8; ++j) {
      int dh = d0 + j;
      int byte = dh * 512 + ((key * 2) ^ ((dh & 7) << 4));
      *reinterpret_cast<ushort*>((char*)Vt + byte) = us[j];
    }
  }
  for (int i = tid; i < 964; i += 512) bias_s[i] = rel[i * 16 + h];

  bf16x8 qf[2][2];
  #pragma unroll
  for (int mi = 0; mi < 2; ++mi)
    #pragma unroll
    for (int s = 0; s < 2; ++s) {
      int q = w * 32 + mi * 16 + c;
      int dh = s * 32 + p4 * 8;
      int4 u = *reinterpret_cast<const int4*>(basep + (size_t)q * 3072 + dh);
      uint32_t a[4] = {(uint32_t)u.x, (uint32_t)u.y, (uint32_t)u.z, (uint32_t)u.w};
      bf16x8 r;
      #pragma unroll
      for (int t = 0; t < 4; ++t) {
        float lo = __uint_as_float(a[t] << 16) * 0.125f;
        float hi = __uint_as_float(a[t] & 0xffff0000u) * 0.125f;
        r[2 * t]     = (short)(__float_as_uint(lo) >> 16);   // exact
        r[2 * t + 1] = (short)(__float_as_uint(hi) >> 16);
      }
      qf[mi][s] = r;
    }
  __syncthreads();

  float m_run[2][4], l_run[2][4];
  f32x4 oacc[2][4];
  #pragma unroll
  for (int mi = 0; mi < 2; ++mi)
    #pragma unroll
    for (int j = 0; j < 4; ++j) {
      m_run[mi][j] = -1e30f; l_run[mi][j] = 0.f;
      oacc[mi][j] = f32x4{0.f, 0.f, 0.f, 0.f};
    }

  ushort* Pw = &Pl[w][0];
  const int colterm = p4 * 4 - c + 15;

  for (int kt = 0; kt < 8; ++kt) {
    f32x4 sacc[2][2];
    #pragma unroll
    for (int mi = 0; mi < 2; ++mi)
      #pragma unroll
      for (int nf = 0; nf < 2; ++nf) {
        int bi = ((w * 2 + mi) - (kt * 2 + nf) + 15) * 31 + colterm;
        #pragma unroll
        for (int j = 0; j < 4; ++j) sacc[mi][nf][j] = bias_s[bi + j];
      }
    #pragma unroll
    for (int nf = 0; nf < 2; ++nf) {
      int key = kt * 32 + nf * 16 + c;
      #pragma unroll
      for (int s = 0; s < 2; ++s) {
        int byte = key * 128 + (((s * 4 + p4) ^ (key & 7)) << 4);
        bf16x8 kb = *reinterpret_cast<const bf16x8*>((const char*)Ks + byte);
        #pragma unroll
        for (int mi = 0; mi < 2; ++mi)
          sacc[mi][nf] = __builtin_amdgcn_mfma_f32_16x16x32_bf16(
              qf[mi][s], kb, sacc[mi][nf], 0, 0, 0);
      }
    }
    float sf[2][4];
    #pragma unroll
    for (int mi = 0; mi < 2; ++mi)
      #pragma unroll
      for (int j = 0; j < 4; ++j) {
        float cm = fmaxf(sacc[mi][0][j], sacc[mi][1][j]);
        cm = fmaxf(cm, __shfl_xor(cm, 1));
        cm = fmaxf(cm, __shfl_xor(cm, 2));
        cm = fmaxf(cm, __shfl_xor(cm, 4));
        cm = fmaxf(cm, __shfl_xor(cm, 8));
        float nm = fmaxf(m_run[mi][j], cm);
        sf[mi][j] = __expf(m_run[mi][j] - nm);
        m_run[mi][j] = nm;
        l_run[mi][j] *= sf[mi][j];
      }
    #pragma unroll
    for (int mi = 0; mi < 2; ++mi)
      #pragma unroll
      for (int nf = 0; nf < 4; ++nf)
        #pragma unroll
        for (int j = 0; j < 4; ++j) oacc[mi][nf][j] *= sf[mi][j];
    #pragma unroll
    for (int mi = 0; mi < 2; ++mi) {
      #pragma unroll
      for (int nf = 0; nf < 2; ++nf)
        #pragma unroll
        for (int j = 0; j < 4; ++j)
          sacc[mi][nf][j] = __expf(sacc[mi][nf][j] - m_run[mi][j]);
      #pragma unroll
      for (int j = 0; j < 4; ++j) {
        float lp = sacc[mi][0][j] + sacc[mi][1][j];
        lp += __shfl_xor(lp, 1);
        lp += __shfl_xor(lp, 2);
        lp += __shfl_xor(lp, 4);
        lp += __shfl_xor(lp, 8);
        l_run[mi][j] += lp;
      }
      #pragma unroll
      for (int nf = 0; nf < 2; ++nf)
        #pragma unroll
        for (int j = 0; j < 4; ++j)
          Pw[(mi * 16 + p4 * 4 + j) * 40 + nf * 16 + c] =
              f2bf_bits(sacc[mi][nf][j]);
    }
    bf16x8 pa[2], vb[4];
    #pragma unroll
    for (int mi = 0; mi < 2; ++mi)
      pa[mi] = *reinterpret_cast<const bf16x8*>(
          (const char*)Pw + (mi * 16 + c) * 80 + p4 * 16);
    #pragma unroll
    for (int nf = 0; nf < 4; ++nf) {
      int dh = nf * 16 + c;
      int byte = dh * 512 + (((kt * 4 + p4) ^ (dh & 7)) << 4);
      vb[nf] = *reinterpret_cast<const bf16x8*>((const char*)Vt + byte);
    }
    #pragma unroll
    for (int mi = 0; mi < 2; ++mi)
      #pragma unroll
      for (int nf = 0; nf < 4; ++nf)
        oacc[mi][nf] = __builtin_amdgcn_mfma_f32_16x16x32_bf16(
            pa[mi], vb[nf], oacc[mi][nf], 0, 0, 0);
  }

  #pragma unroll
  for (int mi = 0; mi < 2; ++mi) {
    float inv[4];
    #pragma unroll
    for (int j = 0; j < 4; ++j) inv[j] = 1.f / l_run[mi][j];
    #pragma unroll
    for (int nf = 0; nf < 4; ++nf)
      #pragma unroll
      for (int j = 0; j < 4; ++j) {
        int q = w * 32 + mi * 16 + p4 * 4 + j;
        int dh = nf * 16 + c;
        o[((size_t)b * 256 + q) * 1024 + h * 64 + dh] =
            __float2bfloat16(oacc[mi][nf][j] * inv[j]);
      }
  }
}

// ------------------------------------------------ cross attention (attn2, MFMA)
// Inputs head-major: q2[b][n][h*64+d], kv[b][m][h*64+d] (+1024 for v).
__global__ __launch_bounds__(512, 1) void attn2_mfma(
    const bf16* __restrict__ q2, const bf16* __restrict__ kv,
    bf16* __restrict__ o2) {
  __shared__ bf16 Ks[80 * 64];            // swizzled rows (128B each), 10 KB
  __shared__ bf16 Vt[64 * 128];           // [dh][key], 256B rows, 16 KB
  __shared__ ushort Pl[8][32 * 104];      // P bf16, stride 104 elems, 52 KB

  const int tid = threadIdx.x;
  const int w = tid >> 6, lane = tid & 63;
  const int p4 = lane >> 4, c = lane & 15;
  const int bh = blockIdx.x, b = bh >> 4, h = bh & 15;
  const size_t kvrow0 = (size_t)b * 77;

  {
    int t16 = tid;                                  // 0..511
    int key = t16 >> 3;
    int sc = ((t16 & 7) ^ (key & 7)) << 3;
    gload_lds16(kv + (kvrow0 + key) * 2048 + h * 64 + sc, (char*)Ks + t16 * 16);
    if (tid < 128) {
      int u16 = 512 + tid; key = u16 >> 3;
      sc = ((u16 & 7) ^ (key & 7)) << 3;
      gload_lds16(kv + (kvrow0 + key) * 2048 + h * 64 + sc, (char*)Ks + u16 * 16);
    }
  }
  for (int i = tid; i < 80 * 8; i += 512) {
    int key = i >> 3, d0 = (i & 7) * 8;
    int4 u = *reinterpret_cast<const int4*>(
        kv + (kvrow0 + key) * 2048 + 1024 + h * 64 + d0);
    const ushort* us = reinterpret_cast<const ushort*>(&u);
    #pragma unroll
    for (int j = 0; j < 8; ++j) {
      int dh = d0 + j;
      int byte = dh * 256 + ((key * 2) ^ ((dh & 7) << 4));
      *reinterpret_cast<ushort*>((char*)Vt + byte) = us[j];
    }
  }
  {
    int row = lane >> 1, colb = 160 + (lane & 1) * 16;
    *reinterpret_cast<int4*>((char*)&Pl[w][0] + row * 208 + colb) =
        int4{0, 0, 0, 0};
  }
  bf16x8 qf[2][2];
  #pragma unroll
  for (int mi = 0; mi < 2; ++mi)
    #pragma unroll
    for (int s = 0; s < 2; ++s) {
      int q = w * 32 + mi * 16 + c;
      int dh = s * 32 + p4 * 8;
      int4 u = *reinterpret_cast<const int4*>(
          q2 + ((size_t)b * 256 + q) * 1024 + h * 64 + dh);
      uint32_t a[4] = {(uint32_t)u.x, (uint32_t)u.y, (uint32_t)u.z, (uint32_t)u.w};
      bf16x8 r;
      #pragma unroll
      for (int t = 0; t < 4; ++t) {
        float lo = __uint_as_float(a[t] << 16) * 0.125f;
        float hi = __uint_as_float(a[t] & 0xffff0000u) * 0.125f;
        r[2 * t]     = (short)(__float_as_uint(lo) >> 16);
        r[2 * t + 1] = (short)(__float_as_uint(hi) >> 16);
      }
      qf[mi][s] = r;
    }
  __syncthreads();

  f32x4 sacc[2][5];
  #pragma unroll
  for (int mi = 0; mi < 2; ++mi)
    #pragma unroll
    for (int nf = 0; nf < 5; ++nf)
      sacc[mi][nf] = f32x4{0.f, 0.f, 0.f, 0.f};
  #pragma unroll
  for (int nf = 0; nf < 5; ++nf) {
    int key = nf * 16 + c;
    #pragma unroll
    for (int s = 0; s < 2; ++s) {
      int byte = key * 128 + (((s * 4 + p4) ^ (key & 7)) << 4);
      bf16x8 kb = *reinterpret_cast<const bf16x8*>((const char*)Ks + byte);
      #pragma unroll
      for (int mi = 0; mi < 2; ++mi)
        sacc[mi][nf] = __builtin_amdgcn_mfma_f32_16x16x32_bf16(
            qf[mi][s], kb, sacc[mi][nf], 0, 0, 0);
    }
  }
  if (c >= 13) {
    #pragma unroll
    for (int mi = 0; mi < 2; ++mi)
      #pragma unroll
      for (int j = 0; j < 4; ++j) sacc[mi][4][j] = -1e30f;
  }
  float lrow[2][4];
  #pragma unroll
  for (int mi = 0; mi < 2; ++mi)
    #pragma unroll
    for (int j = 0; j < 4; ++j) {
      float cm = sacc[mi][0][j];
      #pragma unroll
      for (int nf = 1; nf < 5; ++nf) cm = fmaxf(cm, sacc[mi][nf][j]);
      cm = fmaxf(cm, __shfl_xor(cm, 1));
      cm = fmaxf(cm, __shfl_xor(cm, 2));
      cm = fmaxf(cm, __shfl_xor(cm, 4));
      cm = fmaxf(cm, __shfl_xor(cm, 8));
      float lp = 0.f;
      #pragma unroll
      for (int nf = 0; nf < 5; ++nf) {
        sacc[mi][nf][j] = __expf(sacc[mi][nf][j] - cm);
        lp += sacc[mi][nf][j];
      }
      lp += __shfl_xor(lp, 1);
      lp += __shfl_xor(lp, 2);
      lp += __shfl_xor(lp, 4);
      lp += __shfl_xor(lp, 8);
      lrow[mi][j] = lp;
    }
  ushort* Pw = &Pl[w][0];
  #pragma unroll
  for (int mi = 0; mi < 2; ++mi)
    #pragma unroll
    for (int nf = 0; nf < 5; ++nf)
      #pragma unroll
      for (int j = 0; j < 4; ++j)
        Pw[(mi * 16 + p4 * 4 + j) * 104 + nf * 16 + c] =
            f2bf_bits(sacc[mi][nf][j]);
  f32x4 oacc[2][4];
  #pragma unroll
  for (int mi = 0; mi < 2; ++mi)
    #pragma unroll
    for (int nf = 0; nf < 4; ++nf) oacc[mi][nf] = f32x4{0.f, 0.f, 0.f, 0.f};
  #pragma unroll
  for (int kk = 0; kk < 3; ++kk) {
    bf16x8 pa[2], vb[4];
    #pragma unroll
    for (int mi = 0; mi < 2; ++mi)
      pa[mi] = *reinterpret_cast<const bf16x8*>(
          (const char*)Pw + (mi * 16 + c) * 208 + kk * 64 + p4 * 16);
    #pragma unroll
    for (int nf = 0; nf < 4; ++nf) {
      int dh = nf * 16 + c;
      int byte = dh * 256 + (((kk * 4 + p4) ^ (dh & 7)) << 4);
      vb[nf] = *reinterpret_cast<const bf16x8*>((const char*)Vt + byte);
    }
    #pragma unroll
    for (int mi = 0; mi < 2; ++mi)
      #pragma unroll
      for (int nf = 0; nf < 4; ++nf)
        oacc[mi][nf] = __builtin_amdgcn_mfma_f32_16x16x32_bf16(
            pa[mi], vb[nf], oacc[mi][nf], 0, 0, 0);
  }
  #pragma unroll
  for (int mi = 0; mi < 2; ++mi) {
    float inv[4];
    #pragma unroll
    for (int j = 0; j < 4; ++j) inv[j] = 1.f / lrow[mi][j];
    #pragma unroll
    for (int nf = 0; nf < 4; ++nf)
      #pragma unroll
      for (int j = 0; j < 4; ++j) {
        int q = w * 32 + mi * 16 + p4 * 4 + j;
        int dh = nf * 16 + c;
        o2[((size_t)b * 256 + q) * 1024 + h * 64 + dh] =
            __float2bfloat16(oacc[mi][nf][j] * inv[j]);
      }
  }
}

// ------------------------------------------------ o2 head-major -> xcur += (d*16+h)
__global__ __launch_bounds__(256) void permute_add(
    const bf16* __restrict__ o2, float* __restrict__ xcur) {
  __shared__ float s_lds[1088];
  const int tid = threadIdx.x;
  const int row0 = blockIdx.x * 4;
  for (int r = 0; r < 4; ++r) {
    const int row = row0 + r;
    #pragma unroll
    for (int i = 0; i < 4; ++i) {
      int cc = i * 256 + tid;
      float v = __bfloat162float(o2[(size_t)row * 1024 + cc]);
      s_lds[cc + (cc >> 4)] = v;
    }
    __syncthreads();
    float4 add;
    #pragma unroll
    for (int t = 0; t < 4; ++t) {
      int ct = tid * 4 + t;
      int src = (ct & 15) * 64 + (ct >> 4);
      (&add.x)[t] = s_lds[src + (src >> 4)];
    }
    float4* xp = reinterpret_cast<float4*>(xcur + (size_t)row * 1024 + tid * 4);
    float4 cur = *xp;
    cur.x += add.x; cur.y += add.y; cur.z += add.z; cur.w += add.w;
    *xp = cur;
    __syncthreads();
  }
}

// ---------------------------------------------------------------- launcher

extern "C" void kernel_launch(void* const* d_in, const int* in_sizes, int n_in,
                              void* d_out, int out_size, void* d_ws, size_t ws_size,
                              hipStream_t stream) {
  (void)in_sizes; (void)n_in; (void)out_size; (void)ws_size;
  const float* x      = (const float*)d_in[0];
  const float* noise  = (const float*)d_in[1];
  const float* y      = (const float*)d_in[2];
  const float* W_qkv  = (const float*)d_in[3];
  const float* b_qkv  = (const float*)d_in[4];
  const float* W_proj = (const float*)d_in[5];
  const float* b_proj = (const float*)d_in[6];
  const float* rel    = (const float*)d_in[7];
  const float* W_ada  = (const float*)d_in[8];
  const float* b_ada  = (const float*)d_in[9];
  const float* W_fc1  = (const float*)d_in[10];
  const float* b_fc1  = (const float*)d_in[11];
  const float* W_fc2  = (const float*)d_in[12];
  const float* b_fc2  = (const float*)d_in[13];
  const float* W_q    = (const float*)d_in[14];
  const float* W_kv   = (const float*)d_in[15];

  char* ws = (char*)d_ws;
  size_t off = 0;
  auto alloc = [&](size_t bytes) {
    char* p = ws + off;
    off = (off + bytes + 255) & ~(size_t)255;
    return p;
  };
  float* ada   = (float*)alloc(32u * 6144 * 4);
  float* xcur  = (float*)alloc(8192u * 1024 * 4);
  bf16* WqkvT  = (bf16*)alloc(3072u * 1024 * 2);
  bf16* WprojT = (bf16*)alloc(1024u * 1024 * 2);
  bf16* WqT    = (bf16*)alloc(1024u * 1024 * 2);
  bf16* WkvT   = (bf16*)alloc(2048u * 1024 * 2);
  bf16* Wfc1T  = (bf16*)alloc(4096u * 1024 * 2);
  bf16* Wfc2T  = (bf16*)alloc(1024u * 4096 * 2);
  bf16* WadaT  = (bf16*)alloc(6144u * 1024 * 2);   // 12.6 MB
  bf16* Apad   = (bf16*)alloc(128u * 1024 * 2);    // silu(noise) padded
  bf16* hbuf   = (bf16*)alloc(8192u * 1024 * 2);
  bf16* big    = (bf16*)alloc(8192u * 4096 * 2);   // qkv / o2 / mlp-h
  bf16* obuf   = (bf16*)alloc(8192u * 1024 * 2);   // attn1 o, then q2
  bf16* kvbuf  = (bf16*)alloc(2560u * 2048 * 2);
  bf16* ybuf   = (bf16*)alloc(2560u * 1024 * 2);
  float* outF  = (float*)d_out;

  // weight prep (W_q / W_kv get head-major column permutation)
  transpose_bf16<0><<<dim3(96, 32), 256, 0, stream>>>(W_qkv, WqkvT, 1024, 3072);
  transpose_bf16<0><<<dim3(32, 32), 256, 0, stream>>>(W_proj, WprojT, 1024, 1024);
  transpose_bf16<1><<<dim3(32, 32), 256, 0, stream>>>(W_q, WqT, 1024, 1024);
  transpose_bf16<2><<<dim3(64, 32), 256, 0, stream>>>(W_kv, WkvT, 1024, 2048);
  transpose_bf16<0><<<dim3(128, 32), 256, 0, stream>>>(W_fc1, Wfc1T, 1024, 4096);
  transpose_bf16<0><<<dim3(32, 128), 256, 0, stream>>>(W_fc2, Wfc2T, 4096, 1024);
  transpose_bf16<0><<<dim3(192, 32), 256, 0, stream>>>(W_ada, WadaT, 1024, 6144);
  conv_y<<<2560 * 1024 / 256, 256, 0, stream>>>(y, ybuf);

  // ada = silu(noise) @ W_ada + b_ada  via skinny MFMA GEMM (M=32 padded to 128)
  silu_pad<<<512, 256, 0, stream>>>(noise, Apad);
  gemm_bf16<EPI_ADAF><<<dim3(48, 1), 256, 0, stream>>>(
      Apad, WadaT, 128, 6144, 1024, b_ada, nullptr, 0, nullptr, ada, nullptr);

  // MSA branch
  ln_mod<<<8192, 256, 0, stream>>>(x, ada, 0, 1024, hbuf);
  gemm_bf16<EPI_STORE><<<dim3(24, 64), 256, 0, stream>>>(
      hbuf, WqkvT, 8192, 3072, 1024, b_qkv, nullptr, 0, nullptr, nullptr, big);
  attn1_mfma<<<512, 512, 0, stream>>>(big, rel, obuf);
  gemm_bf16<EPI_PROJ><<<dim3(8, 64), 256, 0, stream>>>(
      obuf, WprojT, 8192, 1024, 1024, b_proj, ada, 2048, x, xcur, hbuf);

  // cross-attention branch (head-major q2/kv)
  gemm_bf16<EPI_STORE><<<dim3(8, 64), 256, 0, stream>>>(
      hbuf, WqT, 8192, 1024, 1024, nullptr, nullptr, 0, nullptr, nullptr, obuf);
  gemm_bf16<EPI_STORE><<<dim3(16, 20), 256, 0, stream>>>(
      ybuf, WkvT, 2560, 2048, 1024, nullptr, nullptr, 0, nullptr, nullptr, kvbuf);
  attn2_mfma<<<512, 512, 0, stream>>>(obuf, kvbuf, big);
  permute_add<<<2048, 256, 0, stream>>>(big, xcur);

  // MLP branch
  ln_mod<<<8192, 256, 0, stream>>>(xcur, ada, 3072, 4096, hbuf);
  gemm_bf16<EPI_GELU><<<dim3(32, 64), 256, 0, stream>>>(
      hbuf, Wfc1T, 8192, 4096, 1024, b_fc1, nullptr, 0, nullptr, nullptr, big);
  gemm_bf16<EPI_OUT><<<dim3(8, 64), 256, 0, stream>>>(
      big, Wfc2T, 8192, 1024, 4096, b_fc2, ada, 5120, xcur, outF, nullptr);
}

// Round 6
// 536.470 us; speedup vs baseline: 2.5310x; 1.0723x over previous
//
#include <hip/hip_runtime.h>
#include <hip/hip_bf16.h>
#include <stdint.h>

typedef __hip_bfloat16 bf16;
using bf16x8 = __attribute__((ext_vector_type(8))) short;   // 8 bf16 (4 VGPRs)
using f32x4  = __attribute__((ext_vector_type(4))) float;   // 4 fp32

// ---------------------------------------------------------------- utilities

__device__ __forceinline__ void gload_lds16(const void* g, void* l) {
  using gchar = __attribute__((address_space(1))) char;
  using lchar = __attribute__((address_space(3))) char;
  gchar* gp = reinterpret_cast<gchar*>(reinterpret_cast<uintptr_t>(g));
  lchar* lp = reinterpret_cast<lchar*>(static_cast<uint32_t>(reinterpret_cast<uintptr_t>(l)));
  __builtin_amdgcn_global_load_lds(gp, lp, 16, 0, 0);
}

__device__ __forceinline__ unsigned short f2bf_bits(float x) {
  uint32_t u = __float_as_uint(x);
  uint32_t r = (u + 0x7fffu + ((u >> 16) & 1u)) >> 16;
  return (unsigned short)r;
}

// ------------------------------------------------ weight transpose fp32->bf16
// W: K x N (row major) -> Wt: N x K bf16.
// PERM=0: identity rows. PERM=1: row n -> (n&15)*64 + (n>>4)  (head-major).
// PERM=2: same permutation applied within each 1024-column half (for W_kv).
template <int PERM>
__global__ __launch_bounds__(256) void transpose_bf16(
    const float* __restrict__ W, bf16* __restrict__ Wt, int K, int N) {
  __shared__ float t[32][33];
  const int n0 = blockIdx.x * 32, k0 = blockIdx.y * 32;
  const int tx = threadIdx.x & 31, ty = threadIdx.x >> 5;
  #pragma unroll
  for (int i = ty; i < 32; i += 8) t[i][tx] = W[(size_t)(k0 + i) * N + n0 + tx];
  __syncthreads();
  #pragma unroll
  for (int i = ty; i < 32; i += 8) {
    int n = n0 + i;
    int np;
    if constexpr (PERM == 0) np = n;
    else if constexpr (PERM == 1) np = (n & 15) * 64 + (n >> 4);
    else { int base = n & 1024, m = n & 1023; np = base + (m & 15) * 64 + (m >> 4); }
    Wt[(size_t)np * K + k0 + tx] = __float2bfloat16(t[tx][i]);
  }
}

// ------------------------------------------------ y -> bf16 (padded to 2560 rows)
__global__ __launch_bounds__(256) void conv_y(
    const float* __restrict__ y, bf16* __restrict__ yb) {
  int i = blockIdx.x * 256 + threadIdx.x;          // < 2560*1024
  float v = (i < 2464 * 1024) ? y[i] : 0.f;
  yb[i] = __float2bfloat16(v);
}

// ------------------------------------------------ silu(noise) -> bf16, pad to 128 rows
__global__ __launch_bounds__(256) void silu_pad(
    const float* __restrict__ noise, bf16* __restrict__ Apad) {
  int i = blockIdx.x * 256 + threadIdx.x;          // over 128*1024
  float v = 0.f;
  if (i < 32 * 1024) {
    float x = noise[i];
    v = x / (1.f + __expf(-x));
  }
  Apad[i] = __float2bfloat16(v);
}

// ------------------------------------------------ LN + modulate -> bf16
__global__ __launch_bounds__(256) void ln_mod(
    const float* __restrict__ x, const float* __restrict__ ada,
    int shOff, int scOff, bf16* __restrict__ out) {
  const int row = blockIdx.x, b = row >> 8, tid = threadIdx.x;
  const float* xr = x + (size_t)row * 1024;
  float v[4], s = 0.f, ss = 0.f;
  #pragma unroll
  for (int i = 0; i < 4; ++i) {
    v[i] = xr[tid + i * 256];
    s += v[i]; ss += v[i] * v[i];
  }
  #pragma unroll
  for (int o = 32; o; o >>= 1) { s += __shfl_xor(s, o); ss += __shfl_xor(ss, o); }
  __shared__ float red[8];
  const int w = tid >> 6;
  if ((tid & 63) == 0) { red[w] = s; red[w + 4] = ss; }
  __syncthreads();
  s = red[0] + red[1] + red[2] + red[3];
  ss = red[4] + red[5] + red[6] + red[7];
  float mu = s * (1.f / 1024.f);
  float var = ss * (1.f / 1024.f) - mu * mu;
  float rstd = rsqrtf(var + 1e-6f);
  const float* adab = ada + (size_t)b * 6144;
  #pragma unroll
  for (int i = 0; i < 4; ++i) {
    int c = tid + i * 256;
    float o = (v[i] - mu) * rstd * (1.f + adab[scOff + c]) + adab[shOff + c];
    out[(size_t)row * 1024 + c] = __float2bfloat16(o);
  }
}

// ------------------------------------------------ generic bf16 MFMA GEMM
// C = A[M,K] @ Bt[N,K]^T ; 128x128 tile, BK=64, 4 waves (64x64 each).
// Flat 1D grid with XCD-aware (G col-groups x P row-parity) mapping:
//   xcd = flat%8 owns col-group xcd/P with row parity xcd%P.
// Keeps per-XCD B-panel set resident in L2 and shrinks the live A window.
enum { EPI_STORE = 0, EPI_GELU = 1, EPI_PROJ = 2, EPI_OUT = 3, EPI_ADAF = 4 };

template <int EPI>
__global__ __launch_bounds__(256, 2) void gemm_bf16(
    const bf16* __restrict__ A, const bf16* __restrict__ Bt,
    int N, int K, int gx, int grpG, int xcdP,
    const float* __restrict__ bias, const float* __restrict__ ada, int adaOff,
    const float* __restrict__ resid, float* __restrict__ outF,
    bf16* __restrict__ outB) {
  __shared__ bf16 As[128 * 64];
  __shared__ bf16 Bs[128 * 64];
  const int tid = threadIdx.x;
  const int w = tid >> 6, lane = tid & 63;
  const int wr = w >> 1, wc = w & 1;
  const int lr = lane >> 4, lc = lane & 15;

  // XCD-aware block mapping (bijective; requires grid%8==0, gx%grpG==0)
  const int flat = blockIdx.x;
  const int xcd = flat & 7, j = flat >> 3;
  const int cpg = gx / grpG;
  const int grp = xcd / xcdP, par = xcd % xcdP;
  const int bx = grp * cpg + j % cpg;
  const int by = (j / cpg) * xcdP + par;
  const int mBase = by * 128, nBase = bx * 128;

  f32x4 acc[4][4];
  #pragma unroll
  for (int mi = 0; mi < 4; ++mi)
    #pragma unroll
    for (int ni = 0; ni < 4; ++ni)
      #pragma unroll
      for (int j2 = 0; j2 < 4; ++j2) acc[mi][ni][j2] = 0.f;

  const int nK = K >> 6;
  for (int ks = 0; ks < nK; ++ks) {
    const int k0 = ks << 6;
    #pragma unroll
    for (int i = 0; i < 4; ++i) {
      int t16 = w * 256 + i * 64 + lane;           // 16B chunk id 0..1023
      int row = t16 >> 3;                          // tile row 0..127
      int cL = ((t16 & 7) ^ (row & 7)) << 3;       // swizzled elem offset in row
      gload_lds16(A + (size_t)(mBase + row) * K + k0 + cL, (char*)As + t16 * 16);
      gload_lds16(Bt + (size_t)(nBase + row) * K + k0 + cL, (char*)Bs + t16 * 16);
    }
    __syncthreads();
    #pragma unroll
    for (int kk = 0; kk < 2; ++kk) {
      bf16x8 af[4], bfr[4];
      #pragma unroll
      for (int mi = 0; mi < 4; ++mi) {
        int row = wr * 64 + mi * 16 + lc;
        int byte = row * 128 + ((kk * 64 + lr * 16) ^ ((row & 7) << 4));
        af[mi] = *reinterpret_cast<const bf16x8*>((const char*)As + byte);
      }
      #pragma unroll
      for (int ni = 0; ni < 4; ++ni) {
        int row = wc * 64 + ni * 16 + lc;
        int byte = row * 128 + ((kk * 64 + lr * 16) ^ ((row & 7) << 4));
        bfr[ni] = *reinterpret_cast<const bf16x8*>((const char*)Bs + byte);
      }
      #pragma unroll
      for (int mi = 0; mi < 4; ++mi)
        #pragma unroll
        for (int ni = 0; ni < 4; ++ni)
          acc[mi][ni] = __builtin_amdgcn_mfma_f32_16x16x32_bf16(
              af[mi], bfr[ni], acc[mi][ni], 0, 0, 0);
    }
    __syncthreads();
  }

  const int rB = mBase + wr * 64, cB = nBase + wc * 64;
  #pragma unroll
  for (int mi = 0; mi < 4; ++mi) {
    #pragma unroll
    for (int ni = 0; ni < 4; ++ni) {
      #pragma unroll
      for (int j2 = 0; j2 < 4; ++j2) {
        int r = rB + mi * 16 + lr * 4 + j2;
        int c = cB + ni * 16 + lc;
        float v = acc[mi][ni][j2];
        if (bias) v += bias[c];
        if constexpr (EPI == EPI_STORE) {
          outB[(size_t)r * N + c] = __float2bfloat16(v);
        } else if constexpr (EPI == EPI_GELU) {
          float e = __expf(1.5957691216057308f * v + 0.07135481627260086f * v * v * v);
          float t = 1.f - 2.f / (e + 1.f);         // tanh, overflow-safe
          outB[(size_t)r * N + c] = __float2bfloat16(0.5f * v * (1.f + t));
        } else if constexpr (EPI == EPI_PROJ) {
          int b = r >> 8;
          float g = ada[(size_t)b * 6144 + adaOff + c];
          float o = resid[(size_t)r * 1024 + c] + g * v;
          outF[(size_t)r * 1024 + c] = o;
          outB[(size_t)r * 1024 + c] = __float2bfloat16(o);
        } else if constexpr (EPI == EPI_OUT) {
          int b = r >> 8;
          float g = ada[(size_t)b * 6144 + adaOff + c];
          outF[(size_t)r * 1024 + c] = resid[(size_t)r * 1024 + c] + g * v;
        } else {  // EPI_ADAF: fp32 store, only real rows (M=32, padded to 128)
          if (r < 32) outF[(size_t)r * N + c] = v;
        }
      }
    }
  }
}

// ------------------------------------------------ window attention (attn1, MFMA)
// block = (b,h), 8 waves x 32 q-rows; flash over 8 key-tiles of 32.
// qkv layout: [b][n][3][h][dh], row stride 3072.
__global__ __launch_bounds__(512, 1) void attn1_mfma(
    const bf16* __restrict__ qkv, const float* __restrict__ rel,
    bf16* __restrict__ o) {
  __shared__ bf16 Ks[256 * 64];          // rows XOR-swizzled in 16B chunks
  __shared__ bf16 Vt[64 * 256];          // V transposed [dh][key], XOR-swizzled
  __shared__ ushort Pl[8][32 * 40];      // per-wave P (bf16 bits), stride 40
  __shared__ float bias_s[964];

  const int tid = threadIdx.x;
  const int w = tid >> 6, lane = tid & 63;
  const int p4 = lane >> 4, c = lane & 15;
  const int bh = blockIdx.x, b = bh >> 4, h = bh & 15;
  const bf16* basep = qkv + (size_t)b * 256 * 3072 + h * 64;

  #pragma unroll
  for (int it = 0; it < 4; ++it) {
    int t16 = it * 512 + tid;                       // 0..2047
    int row = t16 >> 3;
    int sc = ((t16 & 7) ^ (row & 7)) << 3;
    gload_lds16(basep + (size_t)row * 3072 + 1024 + sc, (char*)Ks + t16 * 16);
  }
  #pragma unroll
  for (int it = 0; it < 4; ++it) {
    int i = it * 512 + tid;                         // chunk id 0..2047
    int key = i >> 3, d0 = (i & 7) * 8;
    int4 u = *reinterpret_cast<const int4*>(basep + (size_t)key * 3072 + 2048 + d0);
    const ushort* us = reinterpret_cast<const ushort*>(&u);
    #pragma unroll
    for (int j = 0; j < 8; ++j) {
      int dh = d0 + j;
      int byte = dh * 512 + ((key * 2) ^ ((dh & 7) << 4));
      *reinterpret_cast<ushort*>((char*)Vt + byte) = us[j];
    }
  }
  for (int i = tid; i < 964; i += 512) bias_s[i] = rel[i * 16 + h];

  bf16x8 qf[2][2];
  #pragma unroll
  for (int mi = 0; mi < 2; ++mi)
    #pragma unroll
    for (int s = 0; s < 2; ++s) {
      int q = w * 32 + mi * 16 + c;
      int dh = s * 32 + p4 * 8;
      int4 u = *reinterpret_cast<const int4*>(basep + (size_t)q * 3072 + dh);
      uint32_t a[4] = {(uint32_t)u.x, (uint32_t)u.y, (uint32_t)u.z, (uint32_t)u.w};
      bf16x8 r;
      #pragma unroll
      for (int t = 0; t < 4; ++t) {
        float lo = __uint_as_float(a[t] << 16) * 0.125f;
        float hi = __uint_as_float(a[t] & 0xffff0000u) * 0.125f;
        r[2 * t]     = (short)(__float_as_uint(lo) >> 16);   // exact
        r[2 * t + 1] = (short)(__float_as_uint(hi) >> 16);
      }
      qf[mi][s] = r;
    }
  __syncthreads();

  float m_run[2][4], l_run[2][4];
  f32x4 oacc[2][4];
  #pragma unroll
  for (int mi = 0; mi < 2; ++mi)
    #pragma unroll
    for (int j = 0; j < 4; ++j) {
      m_run[mi][j] = -1e30f; l_run[mi][j] = 0.f;
      oacc[mi][j] = f32x4{0.f, 0.f, 0.f, 0.f};
    }

  ushort* Pw = &Pl[w][0];
  const int colterm = p4 * 4 - c + 15;

  for (int kt = 0; kt < 8; ++kt) {
    f32x4 sacc[2][2];
    #pragma unroll
    for (int mi = 0; mi < 2; ++mi)
      #pragma unroll
      for (int nf = 0; nf < 2; ++nf) {
        int bi = ((w * 2 + mi) - (kt * 2 + nf) + 15) * 31 + colterm;
        #pragma unroll
        for (int j = 0; j < 4; ++j) sacc[mi][nf][j] = bias_s[bi + j];
      }
    #pragma unroll
    for (int nf = 0; nf < 2; ++nf) {
      int key = kt * 32 + nf * 16 + c;
      #pragma unroll
      for (int s = 0; s < 2; ++s) {
        int byte = key * 128 + (((s * 4 + p4) ^ (key & 7)) << 4);
        bf16x8 kb = *reinterpret_cast<const bf16x8*>((const char*)Ks + byte);
        #pragma unroll
        for (int mi = 0; mi < 2; ++mi)
          sacc[mi][nf] = __builtin_amdgcn_mfma_f32_16x16x32_bf16(
              qf[mi][s], kb, sacc[mi][nf], 0, 0, 0);
      }
    }
    float sf[2][4];
    #pragma unroll
    for (int mi = 0; mi < 2; ++mi)
      #pragma unroll
      for (int j = 0; j < 4; ++j) {
        float cm = fmaxf(sacc[mi][0][j], sacc[mi][1][j]);
        cm = fmaxf(cm, __shfl_xor(cm, 1));
        cm = fmaxf(cm, __shfl_xor(cm, 2));
        cm = fmaxf(cm, __shfl_xor(cm, 4));
        cm = fmaxf(cm, __shfl_xor(cm, 8));
        float nm = fmaxf(m_run[mi][j], cm);
        sf[mi][j] = __expf(m_run[mi][j] - nm);
        m_run[mi][j] = nm;
        l_run[mi][j] *= sf[mi][j];
      }
    #pragma unroll
    for (int mi = 0; mi < 2; ++mi)
      #pragma unroll
      for (int nf = 0; nf < 4; ++nf)
        #pragma unroll
        for (int j = 0; j < 4; ++j) oacc[mi][nf][j] *= sf[mi][j];
    #pragma unroll
    for (int mi = 0; mi < 2; ++mi) {
      #pragma unroll
      for (int nf = 0; nf < 2; ++nf)
        #pragma unroll
        for (int j = 0; j < 4; ++j)
          sacc[mi][nf][j] = __expf(sacc[mi][nf][j] - m_run[mi][j]);
      #pragma unroll
      for (int j = 0; j < 4; ++j) {
        float lp = sacc[mi][0][j] + sacc[mi][1][j];
        lp += __shfl_xor(lp, 1);
        lp += __shfl_xor(lp, 2);
        lp += __shfl_xor(lp, 4);
        lp += __shfl_xor(lp, 8);
        l_run[mi][j] += lp;
      }
      #pragma unroll
      for (int nf = 0; nf < 2; ++nf)
        #pragma unroll
        for (int j = 0; j < 4; ++j)
          Pw[(mi * 16 + p4 * 4 + j) * 40 + nf * 16 + c] =
              f2bf_bits(sacc[mi][nf][j]);
    }
    bf16x8 pa[2], vb[4];
    #pragma unroll
    for (int mi = 0; mi < 2; ++mi)
      pa[mi] = *reinterpret_cast<const bf16x8*>(
          (const char*)Pw + (mi * 16 + c) * 80 + p4 * 16);
    #pragma unroll
    for (int nf = 0; nf < 4; ++nf) {
      int dh = nf * 16 + c;
      int byte = dh * 512 + (((kt * 4 + p4) ^ (dh & 7)) << 4);
      vb[nf] = *reinterpret_cast<const bf16x8*>((const char*)Vt + byte);
    }
    #pragma unroll
    for (int mi = 0; mi < 2; ++mi)
      #pragma unroll
      for (int nf = 0; nf < 4; ++nf)
        oacc[mi][nf] = __builtin_amdgcn_mfma_f32_16x16x32_bf16(
            pa[mi], vb[nf], oacc[mi][nf], 0, 0, 0);
  }

  #pragma unroll
  for (int mi = 0; mi < 2; ++mi) {
    float inv[4];
    #pragma unroll
    for (int j = 0; j < 4; ++j) inv[j] = 1.f / l_run[mi][j];
    #pragma unroll
    for (int nf = 0; nf < 4; ++nf)
      #pragma unroll
      for (int j = 0; j < 4; ++j) {
        int q = w * 32 + mi * 16 + p4 * 4 + j;
        int dh = nf * 16 + c;
        o[((size_t)b * 256 + q) * 1024 + h * 64 + dh] =
            __float2bfloat16(oacc[mi][nf][j] * inv[j]);
      }
  }
}

// ------------------------------------------------ cross attention (attn2, MFMA)
// Inputs head-major: q2[b][n][h*64+d], kv[b][m][h*64+d] (+1024 for v).
__global__ __launch_bounds__(512, 1) void attn2_mfma(
    const bf16* __restrict__ q2, const bf16* __restrict__ kv,
    bf16* __restrict__ o2) {
  __shared__ bf16 Ks[80 * 64];            // swizzled rows (128B each), 10 KB
  __shared__ bf16 Vt[64 * 128];           // [dh][key], 256B rows, 16 KB
  __shared__ ushort Pl[8][32 * 104];      // P bf16, stride 104 elems, 52 KB

  const int tid = threadIdx.x;
  const int w = tid >> 6, lane = tid & 63;
  const int p4 = lane >> 4, c = lane & 15;
  const int bh = blockIdx.x, b = bh >> 4, h = bh & 15;
  const size_t kvrow0 = (size_t)b * 77;

  {
    int t16 = tid;                                  // 0..511
    int key = t16 >> 3;
    int sc = ((t16 & 7) ^ (key & 7)) << 3;
    gload_lds16(kv + (kvrow0 + key) * 2048 + h * 64 + sc, (char*)Ks + t16 * 16);
    if (tid < 128) {
      int u16 = 512 + tid; key = u16 >> 3;
      sc = ((u16 & 7) ^ (key & 7)) << 3;
      gload_lds16(kv + (kvrow0 + key) * 2048 + h * 64 + sc, (char*)Ks + u16 * 16);
    }
  }
  for (int i = tid; i < 80 * 8; i += 512) {
    int key = i >> 3, d0 = (i & 7) * 8;
    int4 u = *reinterpret_cast<const int4*>(
        kv + (kvrow0 + key) * 2048 + 1024 + h * 64 + d0);
    const ushort* us = reinterpret_cast<const ushort*>(&u);
    #pragma unroll
    for (int j = 0; j < 8; ++j) {
      int dh = d0 + j;
      int byte = dh * 256 + ((key * 2) ^ ((dh & 7) << 4));
      *reinterpret_cast<ushort*>((char*)Vt + byte) = us[j];
    }
  }
  {
    int row = lane >> 1, colb = 160 + (lane & 1) * 16;
    *reinterpret_cast<int4*>((char*)&Pl[w][0] + row * 208 + colb) =
        int4{0, 0, 0, 0};
  }
  bf16x8 qf[2][2];
  #pragma unroll
  for (int mi = 0; mi < 2; ++mi)
    #pragma unroll
    for (int s = 0; s < 2; ++s) {
      int q = w * 32 + mi * 16 + c;
      int dh = s * 32 + p4 * 8;
      int4 u = *reinterpret_cast<const int4*>(
          q2 + ((size_t)b * 256 + q) * 1024 + h * 64 + dh);
      uint32_t a[4] = {(uint32_t)u.x, (uint32_t)u.y, (uint32_t)u.z, (uint32_t)u.w};
      bf16x8 r;
      #pragma unroll
      for (int t = 0; t < 4; ++t) {
        float lo = __uint_as_float(a[t] << 16) * 0.125f;
        float hi = __uint_as_float(a[t] & 0xffff0000u) * 0.125f;
        r[2 * t]     = (short)(__float_as_uint(lo) >> 16);
        r[2 * t + 1] = (short)(__float_as_uint(hi) >> 16);
      }
      qf[mi][s] = r;
    }
  __syncthreads();

  f32x4 sacc[2][5];
  #pragma unroll
  for (int mi = 0; mi < 2; ++mi)
    #pragma unroll
    for (int nf = 0; nf < 5; ++nf)
      sacc[mi][nf] = f32x4{0.f, 0.f, 0.f, 0.f};
  #pragma unroll
  for (int nf = 0; nf < 5; ++nf) {
    int key = nf * 16 + c;
    #pragma unroll
    for (int s = 0; s < 2; ++s) {
      int byte = key * 128 + (((s * 4 + p4) ^ (key & 7)) << 4);
      bf16x8 kb = *reinterpret_cast<const bf16x8*>((const char*)Ks + byte);
      #pragma unroll
      for (int mi = 0; mi < 2; ++mi)
        sacc[mi][nf] = __builtin_amdgcn_mfma_f32_16x16x32_bf16(
            qf[mi][s], kb, sacc[mi][nf], 0, 0, 0);
    }
  }
  if (c >= 13) {
    #pragma unroll
    for (int mi = 0; mi < 2; ++mi)
      #pragma unroll
      for (int j = 0; j < 4; ++j) sacc[mi][4][j] = -1e30f;
  }
  float lrow[2][4];
  #pragma unroll
  for (int mi = 0; mi < 2; ++mi)
    #pragma unroll
    for (int j = 0; j < 4; ++j) {
      float cm = sacc[mi][0][j];
      #pragma unroll
      for (int nf = 1; nf < 5; ++nf) cm = fmaxf(cm, sacc[mi][nf][j]);
      cm = fmaxf(cm, __shfl_xor(cm, 1));
      cm = fmaxf(cm, __shfl_xor(cm, 2));
      cm = fmaxf(cm, __shfl_xor(cm, 4));
      cm = fmaxf(cm, __shfl_xor(cm, 8));
      float lp = 0.f;
      #pragma unroll
      for (int nf = 0; nf < 5; ++nf) {
        sacc[mi][nf][j] = __expf(sacc[mi][nf][j] - cm);
        lp += sacc[mi][nf][j];
      }
      lp += __shfl_xor(lp, 1);
      lp += __shfl_xor(lp, 2);
      lp += __shfl_xor(lp, 4);
      lp += __shfl_xor(lp, 8);
      lrow[mi][j] = lp;
    }
  ushort* Pw = &Pl[w][0];
  #pragma unroll
  for (int mi = 0; mi < 2; ++mi)
    #pragma unroll
    for (int nf = 0; nf < 5; ++nf)
      #pragma unroll
      for (int j = 0; j < 4; ++j)
        Pw[(mi * 16 + p4 * 4 + j) * 104 + nf * 16 + c] =
            f2bf_bits(sacc[mi][nf][j]);
  f32x4 oacc[2][4];
  #pragma unroll
  for (int mi = 0; mi < 2; ++mi)
    #pragma unroll
    for (int nf = 0; nf < 4; ++nf) oacc[mi][nf] = f32x4{0.f, 0.f, 0.f, 0.f};
  #pragma unroll
  for (int kk = 0; kk < 3; ++kk) {
    bf16x8 pa[2], vb[4];
    #pragma unroll
    for (int mi = 0; mi < 2; ++mi)
      pa[mi] = *reinterpret_cast<const bf16x8*>(
          (const char*)Pw + (mi * 16 + c) * 208 + kk * 64 + p4 * 16);
    #pragma unroll
    for (int nf = 0; nf < 4; ++nf) {
      int dh = nf * 16 + c;
      int byte = dh * 256 + (((kk * 4 + p4) ^ (dh & 7)) << 4);
      vb[nf] = *reinterpret_cast<const bf16x8*>((const char*)Vt + byte);
    }
    #pragma unroll
    for (int mi = 0; mi < 2; ++mi)
      #pragma unroll
      for (int nf = 0; nf < 4; ++nf)
        oacc[mi][nf] = __builtin_amdgcn_mfma_f32_16x16x32_bf16(
            pa[mi], vb[nf], oacc[mi][nf], 0, 0, 0);
  }
  #pragma unroll
  for (int mi = 0; mi < 2; ++mi) {
    float inv[4];
    #pragma unroll
    for (int j = 0; j < 4; ++j) inv[j] = 1.f / lrow[mi][j];
    #pragma unroll
    for (int nf = 0; nf < 4; ++nf)
      #pragma unroll
      for (int j = 0; j < 4; ++j) {
        int q = w * 32 + mi * 16 + p4 * 4 + j;
        int dh = nf * 16 + c;
        o2[((size_t)b * 256 + q) * 1024 + h * 64 + dh] =
            __float2bfloat16(oacc[mi][nf][j] * inv[j]);
      }
  }
}

// ------------------------------------------------ o2 head-major -> xcur += (d*16+h)
__global__ __launch_bounds__(256) void permute_add(
    const bf16* __restrict__ o2, float* __restrict__ xcur) {
  __shared__ float s_lds[1088];
  const int tid = threadIdx.x;
  const int row0 = blockIdx.x * 4;
  for (int r = 0; r < 4; ++r) {
    const int row = row0 + r;
    #pragma unroll
    for (int i = 0; i < 4; ++i) {
      int cc = i * 256 + tid;
      float v = __bfloat162float(o2[(size_t)row * 1024 + cc]);
      s_lds[cc + (cc >> 4)] = v;
    }
    __syncthreads();
    float4 add;
    #pragma unroll
    for (int t = 0; t < 4; ++t) {
      int ct = tid * 4 + t;
      int src = (ct & 15) * 64 + (ct >> 4);
      (&add.x)[t] = s_lds[src + (src >> 4)];
    }
    float4* xp = reinterpret_cast<float4*>(xcur + (size_t)row * 1024 + tid * 4);
    float4 cur = *xp;
    cur.x += add.x; cur.y += add.y; cur.z += add.z; cur.w += add.w;
    *xp = cur;
    __syncthreads();
  }
}

// ---------------------------------------------------------------- launcher

extern "C" void kernel_launch(void* const* d_in, const int* in_sizes, int n_in,
                              void* d_out, int out_size, void* d_ws, size_t ws_size,
                              hipStream_t stream) {
  (void)in_sizes; (void)n_in; (void)out_size; (void)ws_size;
  const float* x      = (const float*)d_in[0];
  const float* noise  = (const float*)d_in[1];
  const float* y      = (const float*)d_in[2];
  const float* W_qkv  = (const float*)d_in[3];
  const float* b_qkv  = (const float*)d_in[4];
  const float* W_proj = (const float*)d_in[5];
  const float* b_proj = (const float*)d_in[6];
  const float* rel    = (const float*)d_in[7];
  const float* W_ada  = (const float*)d_in[8];
  const float* b_ada  = (const float*)d_in[9];
  const float* W_fc1  = (const float*)d_in[10];
  const float* b_fc1  = (const float*)d_in[11];
  const float* W_fc2  = (const float*)d_in[12];
  const float* b_fc2  = (const float*)d_in[13];
  const float* W_q    = (const float*)d_in[14];
  const float* W_kv   = (const float*)d_in[15];

  char* ws = (char*)d_ws;
  size_t off = 0;
  auto alloc = [&](size_t bytes) {
    char* p = ws + off;
    off = (off + bytes + 255) & ~(size_t)255;
    return p;
  };
  float* ada   = (float*)alloc(32u * 6144 * 4);
  float* xcur  = (float*)alloc(8192u * 1024 * 4);
  bf16* WqkvT  = (bf16*)alloc(3072u * 1024 * 2);
  bf16* WprojT = (bf16*)alloc(1024u * 1024 * 2);
  bf16* WqT    = (bf16*)alloc(1024u * 1024 * 2);
  bf16* WkvT   = (bf16*)alloc(2048u * 1024 * 2);
  bf16* Wfc1T  = (bf16*)alloc(4096u * 1024 * 2);
  bf16* Wfc2T  = (bf16*)alloc(1024u * 4096 * 2);
  bf16* WadaT  = (bf16*)alloc(6144u * 1024 * 2);   // 12.6 MB
  bf16* Apad   = (bf16*)alloc(128u * 1024 * 2);    // silu(noise) padded
  bf16* hbuf   = (bf16*)alloc(8192u * 1024 * 2);
  bf16* big    = (bf16*)alloc(8192u * 4096 * 2);   // qkv / o2 / mlp-h
  bf16* obuf   = (bf16*)alloc(8192u * 1024 * 2);   // attn1 o, then q2
  bf16* kvbuf  = (bf16*)alloc(2560u * 2048 * 2);
  bf16* ybuf   = (bf16*)alloc(2560u * 1024 * 2);
  float* outF  = (float*)d_out;

  // weight prep (W_q / W_kv get head-major column permutation)
  transpose_bf16<0><<<dim3(96, 32), 256, 0, stream>>>(W_qkv, WqkvT, 1024, 3072);
  transpose_bf16<0><<<dim3(32, 32), 256, 0, stream>>>(W_proj, WprojT, 1024, 1024);
  transpose_bf16<1><<<dim3(32, 32), 256, 0, stream>>>(W_q, WqT, 1024, 1024);
  transpose_bf16<2><<<dim3(64, 32), 256, 0, stream>>>(W_kv, WkvT, 1024, 2048);
  transpose_bf16<0><<<dim3(128, 32), 256, 0, stream>>>(W_fc1, Wfc1T, 1024, 4096);
  transpose_bf16<0><<<dim3(32, 128), 256, 0, stream>>>(W_fc2, Wfc2T, 4096, 1024);
  transpose_bf16<0><<<dim3(192, 32), 256, 0, stream>>>(W_ada, WadaT, 1024, 6144);
  conv_y<<<2560 * 1024 / 256, 256, 0, stream>>>(y, ybuf);

  // ada = silu(noise) @ W_ada + b_ada  via skinny MFMA GEMM (M=32 padded to 128)
  silu_pad<<<512, 256, 0, stream>>>(noise, Apad);
  gemm_bf16<EPI_ADAF><<<48, 256, 0, stream>>>(
      Apad, WadaT, 6144, 1024, 48, 8, 1, b_ada, nullptr, 0, nullptr, ada, nullptr);

  // MSA branch
  ln_mod<<<8192, 256, 0, stream>>>(x, ada, 0, 1024, hbuf);
  gemm_bf16<EPI_STORE><<<1536, 256, 0, stream>>>(          // qkv: 24x64 tiles
      hbuf, WqkvT, 3072, 1024, 24, 4, 2, b_qkv, nullptr, 0, nullptr, nullptr, big);
  attn1_mfma<<<512, 512, 0, stream>>>(big, rel, obuf);
  gemm_bf16<EPI_PROJ><<<512, 256, 0, stream>>>(            // proj: 8x64 tiles
      obuf, WprojT, 1024, 1024, 8, 1, 8, b_proj, ada, 2048, x, xcur, hbuf);

  // cross-attention branch (head-major q2/kv)
  gemm_bf16<EPI_STORE><<<512, 256, 0, stream>>>(           // q2: 8x64 tiles
      hbuf, WqT, 1024, 1024, 8, 1, 8, nullptr, nullptr, 0, nullptr, nullptr, obuf);
  gemm_bf16<EPI_STORE><<<320, 256, 0, stream>>>(           // kv: 16x20 tiles
      ybuf, WkvT, 2048, 1024, 16, 8, 1, nullptr, nullptr, 0, nullptr, nullptr, kvbuf);
  attn2_mfma<<<512, 512, 0, stream>>>(obuf, kvbuf, big);
  permute_add<<<2048, 256, 0, stream>>>(big, xcur);

  // MLP branch
  ln_mod<<<8192, 256, 0, stream>>>(xcur, ada, 3072, 4096, hbuf);
  gemm_bf16<EPI_GELU><<<2048, 256, 0, stream>>>(           // fc1: 32x64 tiles
      hbuf, Wfc1T, 4096, 1024, 32, 4, 2, b_fc1, nullptr, 0, nullptr, nullptr, big);
  gemm_bf16<EPI_OUT><<<512, 256, 0, stream>>>(             // fc2: 8x64 tiles
      big, Wfc2T, 1024, 4096, 8, 1, 8, b_fc2, ada, 5120, xcur, outF, nullptr);
}

// Round 7
// 518.053 us; speedup vs baseline: 2.6210x; 1.0355x over previous
//
#include <hip/hip_runtime.h>
#include <hip/hip_bf16.h>
#include <stdint.h>

typedef __hip_bfloat16 bf16;
using bf16x8 = __attribute__((ext_vector_type(8))) short;   // 8 bf16 (4 VGPRs)
using f32x4  = __attribute__((ext_vector_type(4))) float;   // 4 fp32

// ---------------------------------------------------------------- utilities

__device__ __forceinline__ void gload_lds16(const void* g, void* l) {
  using gchar = __attribute__((address_space(1))) char;
  using lchar = __attribute__((address_space(3))) char;
  gchar* gp = reinterpret_cast<gchar*>(reinterpret_cast<uintptr_t>(g));
  lchar* lp = reinterpret_cast<lchar*>(static_cast<uint32_t>(reinterpret_cast<uintptr_t>(l)));
  __builtin_amdgcn_global_load_lds(gp, lp, 16, 0, 0);
}

__device__ __forceinline__ unsigned short f2bf_bits(float x) {
  uint32_t u = __float_as_uint(x);
  uint32_t r = (u + 0x7fffu + ((u >> 16) & 1u)) >> 16;
  return (unsigned short)r;
}

// ------------------------------------------------ weight transpose fp32->bf16
// W: K x N (row major) -> Wt: N x K bf16.
// PERM=0: identity rows. PERM=1: row n -> (n&15)*64 + (n>>4)  (head-major).
// PERM=2: same permutation applied within each 1024-column half (for W_kv).
template <int PERM>
__global__ __launch_bounds__(256) void transpose_bf16(
    const float* __restrict__ W, bf16* __restrict__ Wt, int K, int N) {
  __shared__ float t[32][33];
  const int n0 = blockIdx.x * 32, k0 = blockIdx.y * 32;
  const int tx = threadIdx.x & 31, ty = threadIdx.x >> 5;
  #pragma unroll
  for (int i = ty; i < 32; i += 8) t[i][tx] = W[(size_t)(k0 + i) * N + n0 + tx];
  __syncthreads();
  #pragma unroll
  for (int i = ty; i < 32; i += 8) {
    int n = n0 + i;
    int np;
    if constexpr (PERM == 0) np = n;
    else if constexpr (PERM == 1) np = (n & 15) * 64 + (n >> 4);
    else { int base = n & 1024, m = n & 1023; np = base + (m & 15) * 64 + (m >> 4); }
    Wt[(size_t)np * K + k0 + tx] = __float2bfloat16(t[tx][i]);
  }
}

// ------------------------------------------------ y -> bf16 (padded to 2560 rows)
__global__ __launch_bounds__(256) void conv_y(
    const float* __restrict__ y, bf16* __restrict__ yb) {
  int i = blockIdx.x * 256 + threadIdx.x;          // < 2560*1024
  float v = (i < 2464 * 1024) ? y[i] : 0.f;
  yb[i] = __float2bfloat16(v);
}

// ------------------------------------------------ silu(noise) -> bf16, pad to 128 rows
__global__ __launch_bounds__(256) void silu_pad(
    const float* __restrict__ noise, bf16* __restrict__ Apad) {
  int i = blockIdx.x * 256 + threadIdx.x;          // over 128*1024
  float v = 0.f;
  if (i < 32 * 1024) {
    float x = noise[i];
    v = x / (1.f + __expf(-x));
  }
  Apad[i] = __float2bfloat16(v);
}

// ------------------------------------------------ LN + modulate -> bf16
__global__ __launch_bounds__(256) void ln_mod(
    const float* __restrict__ x, const float* __restrict__ ada,
    int shOff, int scOff, bf16* __restrict__ out) {
  const int row = blockIdx.x, b = row >> 8, tid = threadIdx.x;
  const float* xr = x + (size_t)row * 1024;
  float v[4], s = 0.f, ss = 0.f;
  #pragma unroll
  for (int i = 0; i < 4; ++i) {
    v[i] = xr[tid + i * 256];
    s += v[i]; ss += v[i] * v[i];
  }
  #pragma unroll
  for (int o = 32; o; o >>= 1) { s += __shfl_xor(s, o); ss += __shfl_xor(ss, o); }
  __shared__ float red[8];
  const int w = tid >> 6;
  if ((tid & 63) == 0) { red[w] = s; red[w + 4] = ss; }
  __syncthreads();
  s = red[0] + red[1] + red[2] + red[3];
  ss = red[4] + red[5] + red[6] + red[7];
  float mu = s * (1.f / 1024.f);
  float var = ss * (1.f / 1024.f) - mu * mu;
  float rstd = rsqrtf(var + 1e-6f);
  const float* adab = ada + (size_t)b * 6144;
  #pragma unroll
  for (int i = 0; i < 4; ++i) {
    int c = tid + i * 256;
    float o = (v[i] - mu) * rstd * (1.f + adab[scOff + c]) + adab[shOff + c];
    out[(size_t)row * 1024 + c] = __float2bfloat16(o);
  }
}

// ------------------------------------------------ generic bf16 MFMA GEMM (128^2)
enum { EPI_STORE = 0, EPI_GELU = 1, EPI_PROJ = 2, EPI_OUT = 3, EPI_ADAF = 4 };

template <int EPI>
__global__ __launch_bounds__(256, 2) void gemm_bf16(
    const bf16* __restrict__ A, const bf16* __restrict__ Bt,
    int N, int K, int gx, int grpG, int xcdP,
    const float* __restrict__ bias, const float* __restrict__ ada, int adaOff,
    const float* __restrict__ resid, float* __restrict__ outF,
    bf16* __restrict__ outB) {
  __shared__ bf16 As[128 * 64];
  __shared__ bf16 Bs[128 * 64];
  const int tid = threadIdx.x;
  const int w = tid >> 6, lane = tid & 63;
  const int wr = w >> 1, wc = w & 1;
  const int lr = lane >> 4, lc = lane & 15;

  // XCD-aware block mapping (bijective; requires grid%8==0, gx%grpG==0)
  const int flat = blockIdx.x;
  const int xcd = flat & 7, j = flat >> 3;
  const int cpg = gx / grpG;
  const int grp = xcd / xcdP, par = xcd % xcdP;
  const int bx = grp * cpg + j % cpg;
  const int by = (j / cpg) * xcdP + par;
  const int mBase = by * 128, nBase = bx * 128;

  f32x4 acc[4][4];
  #pragma unroll
  for (int mi = 0; mi < 4; ++mi)
    #pragma unroll
    for (int ni = 0; ni < 4; ++ni)
      #pragma unroll
      for (int j2 = 0; j2 < 4; ++j2) acc[mi][ni][j2] = 0.f;

  const int nK = K >> 6;
  for (int ks = 0; ks < nK; ++ks) {
    const int k0 = ks << 6;
    #pragma unroll
    for (int i = 0; i < 4; ++i) {
      int t16 = w * 256 + i * 64 + lane;           // 16B chunk id 0..1023
      int row = t16 >> 3;                          // tile row 0..127
      int cL = ((t16 & 7) ^ (row & 7)) << 3;       // swizzled elem offset in row
      gload_lds16(A + (size_t)(mBase + row) * K + k0 + cL, (char*)As + t16 * 16);
      gload_lds16(Bt + (size_t)(nBase + row) * K + k0 + cL, (char*)Bs + t16 * 16);
    }
    __syncthreads();
    #pragma unroll
    for (int kk = 0; kk < 2; ++kk) {
      bf16x8 af[4], bfr[4];
      #pragma unroll
      for (int mi = 0; mi < 4; ++mi) {
        int row = wr * 64 + mi * 16 + lc;
        int byte = row * 128 + ((kk * 64 + lr * 16) ^ ((row & 7) << 4));
        af[mi] = *reinterpret_cast<const bf16x8*>((const char*)As + byte);
      }
      #pragma unroll
      for (int ni = 0; ni < 4; ++ni) {
        int row = wc * 64 + ni * 16 + lc;
        int byte = row * 128 + ((kk * 64 + lr * 16) ^ ((row & 7) << 4));
        bfr[ni] = *reinterpret_cast<const bf16x8*>((const char*)Bs + byte);
      }
      #pragma unroll
      for (int mi = 0; mi < 4; ++mi)
        #pragma unroll
        for (int ni = 0; ni < 4; ++ni)
          acc[mi][ni] = __builtin_amdgcn_mfma_f32_16x16x32_bf16(
              af[mi], bfr[ni], acc[mi][ni], 0, 0, 0);
    }
    __syncthreads();
  }

  const int rB = mBase + wr * 64, cB = nBase + wc * 64;
  #pragma unroll
  for (int mi = 0; mi < 4; ++mi) {
    #pragma unroll
    for (int ni = 0; ni < 4; ++ni) {
      #pragma unroll
      for (int j2 = 0; j2 < 4; ++j2) {
        int r = rB + mi * 16 + lr * 4 + j2;
        int c = cB + ni * 16 + lc;
        float v = acc[mi][ni][j2];
        if (bias) v += bias[c];
        if constexpr (EPI == EPI_STORE) {
          outB[(size_t)r * N + c] = __float2bfloat16(v);
        } else if constexpr (EPI == EPI_GELU) {
          float e = __expf(1.5957691216057308f * v + 0.07135481627260086f * v * v * v);
          float t = 1.f - 2.f / (e + 1.f);         // tanh, overflow-safe
          outB[(size_t)r * N + c] = __float2bfloat16(0.5f * v * (1.f + t));
        } else if constexpr (EPI == EPI_PROJ) {
          int b = r >> 8;
          float g = ada[(size_t)b * 6144 + adaOff + c];
          float o = resid[(size_t)r * 1024 + c] + g * v;
          outF[(size_t)r * 1024 + c] = o;
          outB[(size_t)r * 1024 + c] = __float2bfloat16(o);
        } else if constexpr (EPI == EPI_OUT) {
          int b = r >> 8;
          float g = ada[(size_t)b * 6144 + adaOff + c];
          outF[(size_t)r * 1024 + c] = resid[(size_t)r * 1024 + c] + g * v;
        } else {  // EPI_ADAF: fp32 store, only real rows (M=32, padded to 128)
          if (r < 32) outF[(size_t)r * N + c] = v;
        }
      }
    }
  }
}

// ------------------------------------------------ 256^2 deep-pipelined GEMM
// 512 threads = 8 waves (2M x 4N); per-wave C = 128x64; BK=64; 2-deep dbuf;
// raw s_barrier + counted vmcnt(8) — prefetch loads stay in flight across
// barriers (T3+T4). LDS 128 KB. Requires M%256==0, N%256==0, K%64==0, K>=128.
template <int EPI>
__global__ __launch_bounds__(512, 1) void gemm256_bf16(
    const bf16* __restrict__ A, const bf16* __restrict__ Bt,
    int N, int K, int gx, int grpG, int xcdP,
    const float* __restrict__ bias, bf16* __restrict__ outB) {
  __shared__ bf16 As[2 * 256 * 64];                // 64 KB
  __shared__ bf16 Bs[2 * 256 * 64];                // 64 KB
  const int tid = threadIdx.x;
  const int w = tid >> 6, lane = tid & 63;
  const int wr = w >> 2, wcn = w & 3;
  const int lr = lane >> 4, lc = lane & 15;

  const int flat = blockIdx.x;
  const int xcd = flat & 7, jj = flat >> 3;
  const int cpg = gx / grpG;
  const int grp = xcd / xcdP, par = xcd % xcdP;
  const int bx = grp * cpg + jj % cpg;
  const int by = (jj / cpg) * xcdP + par;
  const int mBase = by * 256, nBase = bx * 256;

  f32x4 acc[8][4];
  #pragma unroll
  for (int mi = 0; mi < 8; ++mi)
    #pragma unroll
    for (int ni = 0; ni < 4; ++ni)
      acc[mi][ni] = f32x4{0.f, 0.f, 0.f, 0.f};

  const int nT = K >> 6;

  // STAGE tile t into buffer bufI: 8 gload_lds per thread (4 A + 4 B)
  auto STAGE = [&](int t, int bufI) {
    const int k0 = t << 6;
    char* Ad = (char*)As + bufI * 32768;
    char* Bd = (char*)Bs + bufI * 32768;
    #pragma unroll
    for (int i = 0; i < 4; ++i) {
      int ck = i * 512 + tid;                      // chunk 0..2047
      int row = ck >> 3;
      int sc = ((ck & 7) ^ (row & 7)) << 3;        // pre-swizzled source col
      gload_lds16(A + (size_t)(mBase + row) * K + k0 + sc, Ad + ck * 16);
      gload_lds16(Bt + (size_t)(nBase + row) * K + k0 + sc, Bd + ck * 16);
    }
  };

  // prologue: tiles 0,1 in flight; wait tile 0 only
  STAGE(0, 0);
  STAGE(1, 1);
  asm volatile("s_waitcnt vmcnt(8)" ::: "memory");
  __builtin_amdgcn_sched_barrier(0);
  __builtin_amdgcn_s_barrier();
  __builtin_amdgcn_sched_barrier(0);

  for (int t = 0; t < nT; ++t) {
    const int cur = t & 1;
    const char* Ab = (const char*)As + cur * 32768;
    const char* Bb = (const char*)Bs + cur * 32768;
    bf16x8 af[2][8], bfr[2][4];
    #pragma unroll
    for (int kk = 0; kk < 2; ++kk) {
      #pragma unroll
      for (int mi = 0; mi < 8; ++mi) {
        int row = wr * 128 + mi * 16 + lc;
        int byte = row * 128 + ((kk * 64 + lr * 16) ^ ((row & 7) << 4));
        af[kk][mi] = *reinterpret_cast<const bf16x8*>(Ab + byte);
      }
      #pragma unroll
      for (int ni = 0; ni < 4; ++ni) {
        int row = wcn * 64 + ni * 16 + lc;
        int byte = row * 128 + ((kk * 64 + lr * 16) ^ ((row & 7) << 4));
        bfr[kk][ni] = *reinterpret_cast<const bf16x8*>(Bb + byte);
      }
    }
    // B1: all waves' frag reads done -> safe to overwrite buf[cur]
    asm volatile("s_waitcnt lgkmcnt(0)" ::: "memory");
    __builtin_amdgcn_sched_barrier(0);
    __builtin_amdgcn_s_barrier();
    __builtin_amdgcn_sched_barrier(0);

    if (t + 2 < nT) STAGE(t + 2, cur);             // loads fly across barriers

    __builtin_amdgcn_s_setprio(1);
    #pragma unroll
    for (int kk = 0; kk < 2; ++kk)
      #pragma unroll
      for (int mi = 0; mi < 8; ++mi)
        #pragma unroll
        for (int ni = 0; ni < 4; ++ni)
          acc[mi][ni] = __builtin_amdgcn_mfma_f32_16x16x32_bf16(
              af[kk][mi], bfr[kk][ni], acc[mi][ni], 0, 0, 0);
    __builtin_amdgcn_s_setprio(0);

    if (t < nT - 1) {
      // B2: tile t+1 must be resident; t+2's 8 loads may stay in flight
      if (t + 2 < nT) {
        asm volatile("s_waitcnt vmcnt(8)" ::: "memory");
      } else {
        asm volatile("s_waitcnt vmcnt(0)" ::: "memory");
      }
      __builtin_amdgcn_sched_barrier(0);
      __builtin_amdgcn_s_barrier();
      __builtin_amdgcn_sched_barrier(0);
    }
  }

  const int rB = mBase + wr * 128, cB = nBase + wcn * 64;
  #pragma unroll
  for (int mi = 0; mi < 8; ++mi) {
    #pragma unroll
    for (int ni = 0; ni < 4; ++ni) {
      #pragma unroll
      for (int j2 = 0; j2 < 4; ++j2) {
        int r = rB + mi * 16 + lr * 4 + j2;
        int c = cB + ni * 16 + lc;
        float v = acc[mi][ni][j2] + bias[c];
        if constexpr (EPI == EPI_STORE) {
          outB[(size_t)r * N + c] = __float2bfloat16(v);
        } else {  // EPI_GELU
          float e = __expf(1.5957691216057308f * v + 0.07135481627260086f * v * v * v);
          float t2 = 1.f - 2.f / (e + 1.f);
          outB[(size_t)r * N + c] = __float2bfloat16(0.5f * v * (1.f + t2));
        }
      }
    }
  }
}

// ------------------------------------------------ window attention (attn1, MFMA)
__global__ __launch_bounds__(512, 1) void attn1_mfma(
    const bf16* __restrict__ qkv, const float* __restrict__ rel,
    bf16* __restrict__ o) {
  __shared__ bf16 Ks[256 * 64];          // rows XOR-swizzled in 16B chunks
  __shared__ bf16 Vt[64 * 256];          // V transposed [dh][key], XOR-swizzled
  __shared__ ushort Pl[8][32 * 40];      // per-wave P (bf16 bits), stride 40
  __shared__ float bias_s[964];

  const int tid = threadIdx.x;
  const int w = tid >> 6, lane = tid & 63;
  const int p4 = lane >> 4, c = lane & 15;
  const int bh = blockIdx.x, b = bh >> 4, h = bh & 15;
  const bf16* basep = qkv + (size_t)b * 256 * 3072 + h * 64;

  #pragma unroll
  for (int it = 0; it < 4; ++it) {
    int t16 = it * 512 + tid;                       // 0..2047
    int row = t16 >> 3;
    int sc = ((t16 & 7) ^ (row & 7)) << 3;
    gload_lds16(basep + (size_t)row * 3072 + 1024 + sc, (char*)Ks + t16 * 16);
  }
  #pragma unroll
  for (int it = 0; it < 4; ++it) {
    int i = it * 512 + tid;                         // chunk id 0..2047
    int key = i >> 3, d0 = (i & 7) * 8;
    int4 u = *reinterpret_cast<const int4*>(basep + (size_t)key * 3072 + 2048 + d0);
    const ushort* us = reinterpret_cast<const ushort*>(&u);
    #pragma unroll
    for (int j = 0; j < 8; ++j) {
      int dh = d0 + j;
      int byte = dh * 512 + ((key * 2) ^ ((dh & 7) << 4));
      *reinterpret_cast<ushort*>((char*)Vt + byte) = us[j];
    }
  }
  for (int i = tid; i < 964; i += 512) bias_s[i] = rel[i * 16 + h];

  bf16x8 qf[2][2];
  #pragma unroll
  for (int mi = 0; mi < 2; ++mi)
    #pragma unroll
    for (int s = 0; s < 2; ++s) {
      int q = w * 32 + mi * 16 + c;
      int dh = s * 32 + p4 * 8;
      int4 u = *reinterpret_cast<const int4*>(basep + (size_t)q * 3072 + dh);
      uint32_t a[4] = {(uint32_t)u.x, (uint32_t)u.y, (uint32_t)u.z, (uint32_t)u.w};
      bf16x8 r;
      #pragma unroll
      for (int t = 0; t < 4; ++t) {
        float lo = __uint_as_float(a[t] << 16) * 0.125f;
        float hi = __uint_as_float(a[t] & 0xffff0000u) * 0.125f;
        r[2 * t]     = (short)(__float_as_uint(lo) >> 16);   // exact
        r[2 * t + 1] = (short)(__float_as_uint(hi) >> 16);
      }
      qf[mi][s] = r;
    }
  __syncthreads();

  float m_run[2][4], l_run[2][4];
  f32x4 oacc[2][4];
  #pragma unroll
  for (int mi = 0; mi < 2; ++mi)
    #pragma unroll
    for (int j = 0; j < 4; ++j) {
      m_run[mi][j] = -1e30f; l_run[mi][j] = 0.f;
      oacc[mi][j] = f32x4{0.f, 0.f, 0.f, 0.f};
    }

  ushort* Pw = &Pl[w][0];
  const int colterm = p4 * 4 - c + 15;

  for (int kt = 0; kt < 8; ++kt) {
    f32x4 sacc[2][2];
    #pragma unroll
    for (int mi = 0; mi < 2; ++mi)
      #pragma unroll
      for (int nf = 0; nf < 2; ++nf) {
        int bi = ((w * 2 + mi) - (kt * 2 + nf) + 15) * 31 + colterm;
        #pragma unroll
        for (int j = 0; j < 4; ++j) sacc[mi][nf][j] = bias_s[bi + j];
      }
    #pragma unroll
    for (int nf = 0; nf < 2; ++nf) {
      int key = kt * 32 + nf * 16 + c;
      #pragma unroll
      for (int s = 0; s < 2; ++s) {
        int byte = key * 128 + (((s * 4 + p4) ^ (key & 7)) << 4);
        bf16x8 kb = *reinterpret_cast<const bf16x8*>((const char*)Ks + byte);
        #pragma unroll
        for (int mi = 0; mi < 2; ++mi)
          sacc[mi][nf] = __builtin_amdgcn_mfma_f32_16x16x32_bf16(
              qf[mi][s], kb, sacc[mi][nf], 0, 0, 0);
      }
    }
    float sf[2][4];
    #pragma unroll
    for (int mi = 0; mi < 2; ++mi)
      #pragma unroll
      for (int j = 0; j < 4; ++j) {
        float cm = fmaxf(sacc[mi][0][j], sacc[mi][1][j]);
        cm = fmaxf(cm, __shfl_xor(cm, 1));
        cm = fmaxf(cm, __shfl_xor(cm, 2));
        cm = fmaxf(cm, __shfl_xor(cm, 4));
        cm = fmaxf(cm, __shfl_xor(cm, 8));
        float nm = fmaxf(m_run[mi][j], cm);
        sf[mi][j] = __expf(m_run[mi][j] - nm);
        m_run[mi][j] = nm;
        l_run[mi][j] *= sf[mi][j];
      }
    #pragma unroll
    for (int mi = 0; mi < 2; ++mi)
      #pragma unroll
      for (int nf = 0; nf < 4; ++nf)
        #pragma unroll
        for (int j = 0; j < 4; ++j) oacc[mi][nf][j] *= sf[mi][j];
    #pragma unroll
    for (int mi = 0; mi < 2; ++mi) {
      #pragma unroll
      for (int nf = 0; nf < 2; ++nf)
        #pragma unroll
        for (int j = 0; j < 4; ++j)
          sacc[mi][nf][j] = __expf(sacc[mi][nf][j] - m_run[mi][j]);
      #pragma unroll
      for (int j = 0; j < 4; ++j) {
        float lp = sacc[mi][0][j] + sacc[mi][1][j];
        lp += __shfl_xor(lp, 1);
        lp += __shfl_xor(lp, 2);
        lp += __shfl_xor(lp, 4);
        lp += __shfl_xor(lp, 8);
        l_run[mi][j] += lp;
      }
      #pragma unroll
      for (int nf = 0; nf < 2; ++nf)
        #pragma unroll
        for (int j = 0; j < 4; ++j)
          Pw[(mi * 16 + p4 * 4 + j) * 40 + nf * 16 + c] =
              f2bf_bits(sacc[mi][nf][j]);
    }
    bf16x8 pa[2], vb[4];
    #pragma unroll
    for (int mi = 0; mi < 2; ++mi)
      pa[mi] = *reinterpret_cast<const bf16x8*>(
          (const char*)Pw + (mi * 16 + c) * 80 + p4 * 16);
    #pragma unroll
    for (int nf = 0; nf < 4; ++nf) {
      int dh = nf * 16 + c;
      int byte = dh * 512 + (((kt * 4 + p4) ^ (dh & 7)) << 4);
      vb[nf] = *reinterpret_cast<const bf16x8*>((const char*)Vt + byte);
    }
    #pragma unroll
    for (int mi = 0; mi < 2; ++mi)
      #pragma unroll
      for (int nf = 0; nf < 4; ++nf)
        oacc[mi][nf] = __builtin_amdgcn_mfma_f32_16x16x32_bf16(
            pa[mi], vb[nf], oacc[mi][nf], 0, 0, 0);
  }

  #pragma unroll
  for (int mi = 0; mi < 2; ++mi) {
    float inv[4];
    #pragma unroll
    for (int j = 0; j < 4; ++j) inv[j] = 1.f / l_run[mi][j];
    #pragma unroll
    for (int nf = 0; nf < 4; ++nf)
      #pragma unroll
      for (int j = 0; j < 4; ++j) {
        int q = w * 32 + mi * 16 + p4 * 4 + j;
        int dh = nf * 16 + c;
        o[((size_t)b * 256 + q) * 1024 + h * 64 + dh] =
            __float2bfloat16(oacc[mi][nf][j] * inv[j]);
      }
  }
}

// ------------------------------------------------ cross attention (attn2, MFMA)
__global__ __launch_bounds__(512, 1) void attn2_mfma(
    const bf16* __restrict__ q2, const bf16* __restrict__ kv,
    bf16* __restrict__ o2) {
  __shared__ bf16 Ks[80 * 64];            // swizzled rows (128B each), 10 KB
  __shared__ bf16 Vt[64 * 128];           // [dh][key], 256B rows, 16 KB
  __shared__ ushort Pl[8][32 * 104];      // P bf16, stride 104 elems, 52 KB

  const int tid = threadIdx.x;
  const int w = tid >> 6, lane = tid & 63;
  const int p4 = lane >> 4, c = lane & 15;
  const int bh = blockIdx.x, b = bh >> 4, h = bh & 15;
  const size_t kvrow0 = (size_t)b * 77;

  {
    int t16 = tid;                                  // 0..511
    int key = t16 >> 3;
    int sc = ((t16 & 7) ^ (key & 7)) << 3;
    gload_lds16(kv + (kvrow0 + key) * 2048 + h * 64 + sc, (char*)Ks + t16 * 16);
    if (tid < 128) {
      int u16 = 512 + tid; key = u16 >> 3;
      sc = ((u16 & 7) ^ (key & 7)) << 3;
      gload_lds16(kv + (kvrow0 + key) * 2048 + h * 64 + sc, (char*)Ks + u16 * 16);
    }
  }
  for (int i = tid; i < 80 * 8; i += 512) {
    int key = i >> 3, d0 = (i & 7) * 8;
    int4 u = *reinterpret_cast<const int4*>(
        kv + (kvrow0 + key) * 2048 + 1024 + h * 64 + d0);
    const ushort* us = reinterpret_cast<const ushort*>(&u);
    #pragma unroll
    for (int j = 0; j < 8; ++j) {
      int dh = d0 + j;
      int byte = dh * 256 + ((key * 2) ^ ((dh & 7) << 4));
      *reinterpret_cast<ushort*>((char*)Vt + byte) = us[j];
    }
  }
  {
    int row = lane >> 1, colb = 160 + (lane & 1) * 16;
    *reinterpret_cast<int4*>((char*)&Pl[w][0] + row * 208 + colb) =
        int4{0, 0, 0, 0};
  }
  bf16x8 qf[2][2];
  #pragma unroll
  for (int mi = 0; mi < 2; ++mi)
    #pragma unroll
    for (int s = 0; s < 2; ++s) {
      int q = w * 32 + mi * 16 + c;
      int dh = s * 32 + p4 * 8;
      int4 u = *reinterpret_cast<const int4*>(
          q2 + ((size_t)b * 256 + q) * 1024 + h * 64 + dh);
      uint32_t a[4] = {(uint32_t)u.x, (uint32_t)u.y, (uint32_t)u.z, (uint32_t)u.w};
      bf16x8 r;
      #pragma unroll
      for (int t = 0; t < 4; ++t) {
        float lo = __uint_as_float(a[t] << 16) * 0.125f;
        float hi = __uint_as_float(a[t] & 0xffff0000u) * 0.125f;
        r[2 * t]     = (short)(__float_as_uint(lo) >> 16);
        r[2 * t + 1] = (short)(__float_as_uint(hi) >> 16);
      }
      qf[mi][s] = r;
    }
  __syncthreads();

  f32x4 sacc[2][5];
  #pragma unroll
  for (int mi = 0; mi < 2; ++mi)
    #pragma unroll
    for (int nf = 0; nf < 5; ++nf)
      sacc[mi][nf] = f32x4{0.f, 0.f, 0.f, 0.f};
  #pragma unroll
  for (int nf = 0; nf < 5; ++nf) {
    int key = nf * 16 + c;
    #pragma unroll
    for (int s = 0; s < 2; ++s) {
      int byte = key * 128 + (((s * 4 + p4) ^ (key & 7)) << 4);
      bf16x8 kb = *reinterpret_cast<const bf16x8*>((const char*)Ks + byte);
      #pragma unroll
      for (int mi = 0; mi < 2; ++mi)
        sacc[mi][nf] = __builtin_amdgcn_mfma_f32_16x16x32_bf16(
            qf[mi][s], kb, sacc[mi][nf], 0, 0, 0);
    }
  }
  if (c >= 13) {
    #pragma unroll
    for (int mi = 0; mi < 2; ++mi)
      #pragma unroll
      for (int j = 0; j < 4; ++j) sacc[mi][4][j] = -1e30f;
  }
  float lrow[2][4];
  #pragma unroll
  for (int mi = 0; mi < 2; ++mi)
    #pragma unroll
    for (int j = 0; j < 4; ++j) {
      float cm = sacc[mi][0][j];
      #pragma unroll
      for (int nf = 1; nf < 5; ++nf) cm = fmaxf(cm, sacc[mi][nf][j]);
      cm = fmaxf(cm, __shfl_xor(cm, 1));
      cm = fmaxf(cm, __shfl_xor(cm, 2));
      cm = fmaxf(cm, __shfl_xor(cm, 4));
      cm = fmaxf(cm, __shfl_xor(cm, 8));
      float lp = 0.f;
      #pragma unroll
      for (int nf = 0; nf < 5; ++nf) {
        sacc[mi][nf][j] = __expf(sacc[mi][nf][j] - cm);
        lp += sacc[mi][nf][j];
      }
      lp += __shfl_xor(lp, 1);
      lp += __shfl_xor(lp, 2);
      lp += __shfl_xor(lp, 4);
      lp += __shfl_xor(lp, 8);
      lrow[mi][j] = lp;
    }
  ushort* Pw = &Pl[w][0];
  #pragma unroll
  for (int mi = 0; mi < 2; ++mi)
    #pragma unroll
    for (int nf = 0; nf < 5; ++nf)
      #pragma unroll
      for (int j = 0; j < 4; ++j)
        Pw[(mi * 16 + p4 * 4 + j) * 104 + nf * 16 + c] =
            f2bf_bits(sacc[mi][nf][j]);
  f32x4 oacc[2][4];
  #pragma unroll
  for (int mi = 0; mi < 2; ++mi)
    #pragma unroll
    for (int nf = 0; nf < 4; ++nf) oacc[mi][nf] = f32x4{0.f, 0.f, 0.f, 0.f};
  #pragma unroll
  for (int kk = 0; kk < 3; ++kk) {
    bf16x8 pa[2], vb[4];
    #pragma unroll
    for (int mi = 0; mi < 2; ++mi)
      pa[mi] = *reinterpret_cast<const bf16x8*>(
          (const char*)Pw + (mi * 16 + c) * 208 + kk * 64 + p4 * 16);
    #pragma unroll
    for (int nf = 0; nf < 4; ++nf) {
      int dh = nf * 16 + c;
      int byte = dh * 256 + (((kk * 4 + p4) ^ (dh & 7)) << 4);
      vb[nf] = *reinterpret_cast<const bf16x8*>((const char*)Vt + byte);
    }
    #pragma unroll
    for (int mi = 0; mi < 2; ++mi)
      #pragma unroll
      for (int nf = 0; nf < 4; ++nf)
        oacc[mi][nf] = __builtin_amdgcn_mfma_f32_16x16x32_bf16(
            pa[mi], vb[nf], oacc[mi][nf], 0, 0, 0);
  }
  #pragma unroll
  for (int mi = 0; mi < 2; ++mi) {
    float inv[4];
    #pragma unroll
    for (int j = 0; j < 4; ++j) inv[j] = 1.f / lrow[mi][j];
    #pragma unroll
    for (int nf = 0; nf < 4; ++nf)
      #pragma unroll
      for (int j = 0; j < 4; ++j) {
        int q = w * 32 + mi * 16 + p4 * 4 + j;
        int dh = nf * 16 + c;
        o2[((size_t)b * 256 + q) * 1024 + h * 64 + dh] =
            __float2bfloat16(oacc[mi][nf][j] * inv[j]);
      }
  }
}

// ------------------------------------------------ o2 head-major -> xcur += (d*16+h)
__global__ __launch_bounds__(256) void permute_add(
    const bf16* __restrict__ o2, float* __restrict__ xcur) {
  __shared__ float s_lds[1088];
  const int tid = threadIdx.x;
  const int row0 = blockIdx.x * 4;
  for (int r = 0; r < 4; ++r) {
    const int row = row0 + r;
    #pragma unroll
    for (int i = 0; i < 4; ++i) {
      int cc = i * 256 + tid;
      float v = __bfloat162float(o2[(size_t)row * 1024 + cc]);
      s_lds[cc + (cc >> 4)] = v;
    }
    __syncthreads();
    float4 add;
    #pragma unroll
    for (int t = 0; t < 4; ++t) {
      int ct = tid * 4 + t;
      int src = (ct & 15) * 64 + (ct >> 4);
      (&add.x)[t] = s_lds[src + (src >> 4)];
    }
    float4* xp = reinterpret_cast<float4*>(xcur + (size_t)row * 1024 + tid * 4);
    float4 cur = *xp;
    cur.x += add.x; cur.y += add.y; cur.z += add.z; cur.w += add.w;
    *xp = cur;
    __syncthreads();
  }
}

// ---------------------------------------------------------------- launcher

extern "C" void kernel_launch(void* const* d_in, const int* in_sizes, int n_in,
                              void* d_out, int out_size, void* d_ws, size_t ws_size,
                              hipStream_t stream) {
  (void)in_sizes; (void)n_in; (void)out_size; (void)ws_size;
  const float* x      = (const float*)d_in[0];
  const float* noise  = (const float*)d_in[1];
  const float* y      = (const float*)d_in[2];
  const float* W_qkv  = (const float*)d_in[3];
  const float* b_qkv  = (const float*)d_in[4];
  const float* W_proj = (const float*)d_in[5];
  const float* b_proj = (const float*)d_in[6];
  const float* rel    = (const float*)d_in[7];
  const float* W_ada  = (const float*)d_in[8];
  const float* b_ada  = (const float*)d_in[9];
  const float* W_fc1  = (const float*)d_in[10];
  const float* b_fc1  = (const float*)d_in[11];
  const float* W_fc2  = (const float*)d_in[12];
  const float* b_fc2  = (const float*)d_in[13];
  const float* W_q    = (const float*)d_in[14];
  const float* W_kv   = (const float*)d_in[15];

  char* ws = (char*)d_ws;
  size_t off = 0;
  auto alloc = [&](size_t bytes) {
    char* p = ws + off;
    off = (off + bytes + 255) & ~(size_t)255;
    return p;
  };
  float* ada   = (float*)alloc(32u * 6144 * 4);
  float* xcur  = (float*)alloc(8192u * 1024 * 4);
  bf16* WqkvT  = (bf16*)alloc(3072u * 1024 * 2);
  bf16* WprojT = (bf16*)alloc(1024u * 1024 * 2);
  bf16* WqT    = (bf16*)alloc(1024u * 1024 * 2);
  bf16* WkvT   = (bf16*)alloc(2048u * 1024 * 2);
  bf16* Wfc1T  = (bf16*)alloc(4096u * 1024 * 2);
  bf16* Wfc2T  = (bf16*)alloc(1024u * 4096 * 2);
  bf16* WadaT  = (bf16*)alloc(6144u * 1024 * 2);   // 12.6 MB
  bf16* Apad   = (bf16*)alloc(128u * 1024 * 2);    // silu(noise) padded
  bf16* hbuf   = (bf16*)alloc(8192u * 1024 * 2);
  bf16* big    = (bf16*)alloc(8192u * 4096 * 2);   // qkv / o2 / mlp-h
  bf16* obuf   = (bf16*)alloc(8192u * 1024 * 2);   // attn1 o, then q2
  bf16* kvbuf  = (bf16*)alloc(2560u * 2048 * 2);
  bf16* ybuf   = (bf16*)alloc(2560u * 1024 * 2);
  float* outF  = (float*)d_out;

  // weight prep (W_q / W_kv get head-major column permutation)
  transpose_bf16<0><<<dim3(96, 32), 256, 0, stream>>>(W_qkv, WqkvT, 1024, 3072);
  transpose_bf16<0><<<dim3(32, 32), 256, 0, stream>>>(W_proj, WprojT, 1024, 1024);
  transpose_bf16<1><<<dim3(32, 32), 256, 0, stream>>>(W_q, WqT, 1024, 1024);
  transpose_bf16<2><<<dim3(64, 32), 256, 0, stream>>>(W_kv, WkvT, 1024, 2048);
  transpose_bf16<0><<<dim3(128, 32), 256, 0, stream>>>(W_fc1, Wfc1T, 1024, 4096);
  transpose_bf16<0><<<dim3(32, 128), 256, 0, stream>>>(W_fc2, Wfc2T, 4096, 1024);
  transpose_bf16<0><<<dim3(192, 32), 256, 0, stream>>>(W_ada, WadaT, 1024, 6144);
  conv_y<<<2560 * 1024 / 256, 256, 0, stream>>>(y, ybuf);

  // ada = silu(noise) @ W_ada + b_ada  via skinny MFMA GEMM (M=32 padded to 128)
  silu_pad<<<512, 256, 0, stream>>>(noise, Apad);
  gemm_bf16<EPI_ADAF><<<48, 256, 0, stream>>>(
      Apad, WadaT, 6144, 1024, 48, 8, 1, b_ada, nullptr, 0, nullptr, ada, nullptr);

  // MSA branch
  ln_mod<<<8192, 256, 0, stream>>>(x, ada, 0, 1024, hbuf);
  gemm256_bf16<EPI_STORE><<<384, 512, 0, stream>>>(      // qkv: 32x12 tiles of 256^2
      hbuf, WqkvT, 3072, 1024, 12, 4, 2, b_qkv, big);
  attn1_mfma<<<512, 512, 0, stream>>>(big, rel, obuf);
  gemm_bf16<EPI_PROJ><<<512, 256, 0, stream>>>(          // proj: 8x64 tiles
      obuf, WprojT, 1024, 1024, 8, 1, 8, b_proj, ada, 2048, x, xcur, hbuf);

  // cross-attention branch (head-major q2/kv)
  gemm_bf16<EPI_STORE><<<512, 256, 0, stream>>>(         // q2: 8x64 tiles
      hbuf, WqT, 1024, 1024, 8, 1, 8, nullptr, nullptr, 0, nullptr, nullptr, obuf);
  gemm_bf16<EPI_STORE><<<320, 256, 0, stream>>>(         // kv: 16x20 tiles
      ybuf, WkvT, 2048, 1024, 16, 8, 1, nullptr, nullptr, 0, nullptr, nullptr, kvbuf);
  attn2_mfma<<<512, 512, 0, stream>>>(obuf, kvbuf, big);
  permute_add<<<2048, 256, 0, stream>>>(big, xcur);

  // MLP branch
  ln_mod<<<8192, 256, 0, stream>>>(xcur, ada, 3072, 4096, hbuf);
  gemm256_bf16<EPI_GELU><<<512, 512, 0, stream>>>(       // fc1: 32x16 tiles of 256^2
      hbuf, Wfc1T, 4096, 1024, 16, 4, 2, b_fc1, big);
  gemm_bf16<EPI_OUT><<<512, 256, 0, stream>>>(           // fc2: 8x64 tiles
      big, Wfc2T, 1024, 4096, 8, 1, 8, b_fc2, ada, 5120, xcur, outF, nullptr);
}